// Round 13
// baseline (182.684 us; speedup 1.0000x reference)
//
#include <hip/hip_runtime.h>
#include <hip/hip_bf16.h>
#include <math.h>

#define N_   64
#define C_   64
#define T_   128
#define V_   25
#define OUT_ 64
#define REL_ 8
#define MID_ 32
#define TV_  (T_*V_)   // 3200
#define VV_  (V_*V_)   // 625
#define TT2  8         // t-tile for fused temporal kernel
#define XTP3 40        // xtl row pad in shorts (80B: 16B-aligned rows)

typedef __hip_bfloat16 bf16;
typedef unsigned int uint;
__device__ __forceinline__ float b2f(bf16 x){ return __bfloat162float(x); }
__device__ __forceinline__ bf16  f2b(float x){ return __float2bfloat16(x); }
__device__ __forceinline__ float bfu(uint u){ return __uint_as_float(u<<16); }
__device__ __forceinline__ float bfh(uint u){ return __uint_as_float(u&0xffff0000u); }
__device__ __forceinline__ float bfs(unsigned short s){ return __uint_as_float(((uint)s)<<16); }

// fast tanh: clamp + (e^{2x}-1)/(e^{2x}+1); abs err ~1e-6, threshold 1.9e-2.
__device__ __forceinline__ float ftanh(float x){
    float cx = fminf(fmaxf(x, -15.f), 15.f);
    float e  = __expf(2.0f*cx);
    return (e - 1.0f) / (e + 1.0f);
}

// LESSONS (measured, R4-R12):
//  * launch_bounds min-waves caps -> VGPR spill -> GBs of scratch traffic (R6-R8). Banned.
//  * k10 acc[25]->acc[13] via wave-uniform v-split: 87->~53us (R12). VGPR reduction
//    must be NATURAL (restructure), never forced.
//  * R4 staging structure (inside-round, after phase-1 compute) is clean.
//  * k1 was LDS-capacity-capped (41.5KB -> 3 blocks/CU): this round moves the
//    broadcast-read weight table from LDS to an L1-resident global layout.

// K0: weights -> padded per-og layout WTgP[c][og][8] (i=0..5 used) + biases Bg[96]
__global__ __launch_bounds__(256) void k0_prep(
    const float* __restrict__ w1, const float* __restrict__ b1,
    const float* __restrict__ w2, const float* __restrict__ b2,
    const float* __restrict__ w11, const float* __restrict__ b11,
    const float* __restrict__ w22, const float* __restrict__ b22,
    const float* __restrict__ w3, const float* __restrict__ b3,
    float* __restrict__ WTgP, float* __restrict__ Bg)
{
    int tid = threadIdx.x;
    for (int e = tid; e < C_*16; e += 256){ WTgP[e*8+6]=0.f; WTgP[e*8+7]=0.f; }
    for (int e = tid; e < 96*C_; e += 256){
        int o = e / C_, c = e % C_;
        float w;
        if      (o < 8)  w = w1[o*C_+c];
        else if (o < 16) w = w2[(o-8)*C_+c];
        else if (o < 24) w = w11[(o-16)*C_+c];
        else if (o < 32) w = w22[(o-24)*C_+c];
        else             w = w3[(o-32)*C_+c];
        WTgP[(c*16 + o/6)*8 + (o%6)] = w;
    }
    if (tid < 96){
        int o = tid; float bb;
        if      (o < 8)  bb = b1[o];
        else if (o < 16) bb = b2[o-8];
        else if (o < 24) bb = b11[o-16];
        else if (o < 32) bb = b22[o-24];
        else             bb = b3[o-32];
        Bg[o] = bb;
    }
}

// K1: all five 1x1 convs. Weights read from L1-resident WTgP (no LDS table)
// -> LDS 16.4KB -> ~9 blocks/CU, occupancy VGPR-capped (~7 waves/SIMD).
__global__ __launch_bounds__(256) void k1_convs(
    const float* __restrict__ x,
    const float* __restrict__ WTgP, const float* __restrict__ Bg,
    float* __restrict__ x1f, float* __restrict__ x2f,
    float* __restrict__ x11f, float* __restrict__ x22f,
    bf16* __restrict__ x3h)
{
    __shared__ __align__(16) float xl[C_*64];    // 16KB
    __shared__ float Bl[96];
    int bid = blockIdx.x;
    int n = bid / 50, jt = bid % 50;
    int j0 = jt * 64;
    int tid = threadIdx.x;
    for (int e = tid; e < 1024; e += 256){
        int c = e >> 4, j4 = e & 15;
        ((float4*)xl)[e] = ((const float4*)(x + (size_t)(n*C_+c)*TV_ + j0))[j4];
    }
    if (tid < 96) Bl[tid] = Bg[tid];
    __syncthreads();

    int og = tid >> 4;
    int jg = tid & 15;
    int o0 = og*6, jj = jg*4;
    const float* wp = WTgP + og*8;
    float acc[6][4];
    #pragma unroll
    for (int i=0;i<6;i++){
        float b = Bl[o0+i];
        #pragma unroll
        for (int q=0;q<4;q++) acc[i][q] = b;
    }
    #pragma unroll 8
    for (int c = 0; c < C_; ++c){
        float4 xv = *(const float4*)&xl[c*64 + jj];
        float4 wa = *(const float4*)(wp + c*128);
        float2 wb = *(const float2*)(wp + c*128 + 4);
        float w0=wa.x, w1_=wa.y, w2_=wa.z, w3_=wa.w, w4_=wb.x, w5_=wb.y;
        acc[0][0]=fmaf(w0,xv.x,acc[0][0]); acc[0][1]=fmaf(w0,xv.y,acc[0][1]);
        acc[0][2]=fmaf(w0,xv.z,acc[0][2]); acc[0][3]=fmaf(w0,xv.w,acc[0][3]);
        acc[1][0]=fmaf(w1_,xv.x,acc[1][0]); acc[1][1]=fmaf(w1_,xv.y,acc[1][1]);
        acc[1][2]=fmaf(w1_,xv.z,acc[1][2]); acc[1][3]=fmaf(w1_,xv.w,acc[1][3]);
        acc[2][0]=fmaf(w2_,xv.x,acc[2][0]); acc[2][1]=fmaf(w2_,xv.y,acc[2][1]);
        acc[2][2]=fmaf(w2_,xv.z,acc[2][2]); acc[2][3]=fmaf(w2_,xv.w,acc[2][3]);
        acc[3][0]=fmaf(w3_,xv.x,acc[3][0]); acc[3][1]=fmaf(w3_,xv.y,acc[3][1]);
        acc[3][2]=fmaf(w3_,xv.z,acc[3][2]); acc[3][3]=fmaf(w3_,xv.w,acc[3][3]);
        acc[4][0]=fmaf(w4_,xv.x,acc[4][0]); acc[4][1]=fmaf(w4_,xv.y,acc[4][1]);
        acc[4][2]=fmaf(w4_,xv.z,acc[4][2]); acc[4][3]=fmaf(w4_,xv.w,acc[4][3]);
        acc[5][0]=fmaf(w5_,xv.x,acc[5][0]); acc[5][1]=fmaf(w5_,xv.y,acc[5][1]);
        acc[5][2]=fmaf(w5_,xv.z,acc[5][2]); acc[5][3]=fmaf(w5_,xv.w,acc[5][3]);
    }
    int pos = j0 + jj;
    #pragma unroll
    for (int i=0;i<6;i++){
        int o = o0 + i;
        float4 v = make_float4(acc[i][0], acc[i][1], acc[i][2], acc[i][3]);
        if      (o < 8)  *(float4*)&x1f [(size_t)(n*REL_+o)     *TV_ + pos] = v;
        else if (o < 16) *(float4*)&x2f [(size_t)(n*REL_+(o-8)) *TV_ + pos] = v;
        else if (o < 24) *(float4*)&x11f[(size_t)(n*REL_+(o-16))*TV_ + pos] = v;
        else if (o < 32) *(float4*)&x22f[(size_t)(n*REL_+(o-24))*TV_ + pos] = v;
        else {
            bf16 h0=f2b(v.x), h1=f2b(v.y), h2=f2b(v.z), h3=f2b(v.w);
            ushort4 pk;
            pk.x = *(unsigned short*)&h0; pk.y = *(unsigned short*)&h1;
            pk.z = *(unsigned short*)&h2; pk.w = *(unsigned short*)&h3;
            *(ushort4*)&x3h[(size_t)(n*OUT_+(o-32))*TV_ + pos] = pk;
        }
    }
}

// Kx3bar v2: coalesced uint4 staging -> LDS fp32 -> two-level reduce.
__global__ __launch_bounds__(256) void k_x3bar2(const bf16* __restrict__ x3h,
                                                float* __restrict__ x3bar)
{
    __shared__ __align__(16) float xf[TV_];   // 12.8KB
    __shared__ float red[V_*8];
    int bid = blockIdx.x;   // n*OUT + c
    int tid = threadIdx.x;
    for (int e = tid; e < 400; e += 256){
        uint4 p = ((const uint4*)(x3h + (size_t)bid*TV_))[e];
        float* d = xf + e*8;
        d[0]=bfu(p.x); d[1]=bfh(p.x); d[2]=bfu(p.y); d[3]=bfh(p.y);
        d[4]=bfu(p.z); d[5]=bfh(p.z); d[6]=bfu(p.w); d[7]=bfh(p.w);
    }
    __syncthreads();
    if (tid < 200){
        int v = tid % V_, g = tid / V_;   // g 0..7 owns 16 t's
        float s = 0.f;
        #pragma unroll
        for (int k=0;k<16;++k) s += xf[(g*16+k)*V_ + v];
        red[g*V_+v] = s;
    }
    __syncthreads();
    if (tid < V_){
        float s = 0.f;
        #pragma unroll
        for (int g=0; g<8; ++g) s += red[g*V_+tid];
        x3bar[(size_t)bid*V_+tid] = s * (1.0f/T_);
    }
}

// K3: att8 = tanh(x1^T x2 / T);  xm = tanh(w5_0*mean_res + w5_1*max_res + b5)*alpha
__global__ __launch_bounds__(256) void k3_att8_xm(
    const float* __restrict__ x1f, const float* __restrict__ x2f,
    const float* __restrict__ w5, const float* __restrict__ b5,
    const int* __restrict__ alpha,
    float* __restrict__ att8, float* __restrict__ xm)
{
    __shared__ __align__(16) float l1[TV_], l2[TV_];
    __shared__ float mu1l[V_], mu2l[V_], m1l[V_], m2l[V_];
    int bid = blockIdx.x;      // n*REL + r
    int tid = threadIdx.x;
    int r = bid % REL_;
    for (int e = tid; e < 800; e += 256){
        ((float4*)l1)[e] = ((const float4*)(x1f + (size_t)bid*TV_))[e];
        ((float4*)l2)[e] = ((const float4*)(x2f + (size_t)bid*TV_))[e];
    }
    __syncthreads();
    if (tid < 50){
        int v = tid % V_;
        const float* L = (tid < V_) ? l1 : l2;
        float s=0.f, mm=-1e30f;
        for (int t=0;t<T_;++t){
            float a = L[t*V_+v];
            s += a; mm = fmaxf(mm, a);
        }
        if (tid < V_){ mu1l[v]=s*(1.0f/T_); m1l[v]=mm; }
        else         { mu2l[v]=s*(1.0f/T_); m2l[v]=mm; }
    }
    __syncthreads();
    float w50=w5[r*2+0], w51=w5[r*2+1], b5r=b5[r];
    float af = (float)alpha[0];
    for (int idx=tid; idx<VV_; idx+=256){
        int u = idx/V_, v = idx%V_;
        float s=0.f;
        for (int t=0;t<T_;++t) s = fmaf(l1[t*V_+u], l2[t*V_+v], s);
        att8[(size_t)bid*VV_+idx] = ftanh(s*(1.0f/T_));
        float mr = mu1l[u]-mu2l[v];
        float xr = m1l[u]-m2l[v];
        xm[(size_t)bid*VV_+idx] = ftanh(fmaf(w50,mr,fmaf(w51,xr,b5r))) * af;
    }
}

// K6v2: channel attention; no attc materialization.
__global__ __launch_bounds__(256) void k6_chatt2(
    const float* __restrict__ att8, const float* __restrict__ x3bar,
    const float* __restrict__ watt, const float* __restrict__ batt,
    const float* __restrict__ wc1, const float* __restrict__ bc1,
    const float* __restrict__ bng, const float* __restrict__ bnb,
    const float* __restrict__ bnm, const float* __restrict__ bnv,
    const float* __restrict__ wc2, const float* __restrict__ bc2,
    float* __restrict__ catt)
{
    __shared__ float rs8[REL_*V_];
    __shared__ float gl[OUT_];
    __shared__ float hl[MID_];
    int n = blockIdx.x, tid = threadIdx.x;
    if (tid < REL_*V_){
        int r = tid / V_, u = tid % V_;
        const float* p = att8 + (size_t)(n*REL_+r)*VV_ + u*V_;
        float s = 0.f;
        #pragma unroll
        for (int v=0;v<V_;++v) s += p[v];
        rs8[tid] = s;
    }
    __syncthreads();
    if (tid < OUT_){
        int c = tid;
        const float* xb = x3bar + (size_t)(n*OUT_+c)*V_;
        float xbr[V_], sb = 0.f;
        #pragma unroll
        for (int u=0;u<V_;++u){ xbr[u]=xb[u]; sb += xbr[u]; }
        float s = 0.f;
        #pragma unroll
        for (int r=0;r<REL_;++r){
            float d = 0.f;
            #pragma unroll
            for (int u=0;u<V_;++u) d = fmaf(xbr[u], rs8[r*V_+u], d);
            s = fmaf(watt[c*REL_+r], d, s);
        }
        gl[c] = (s + (float)V_*batt[c]*sb) * (1.0f/(float)V_);
    }
    __syncthreads();
    if (tid < MID_){
        float h = bc1[tid];
        for (int c=0;c<OUT_;++c) h = fmaf(wc1[tid*OUT_+c], gl[c], h);
        h = (h - bnm[tid]) * bng[tid] * rsqrtf(bnv[tid] + 1e-5f) + bnb[tid];
        h = 0.5f*h*(1.0f+erff(h*0.70710678118654752f));
        hl[tid]=h;
    }
    __syncthreads();
    if (tid < OUT_){
        float s = bc2[tid];
        for (int m=0;m<MID_;++m) s = fmaf(wc2[tid*MID_+m], hl[m], s);
        catt[n*OUT_+tid] = 1.0f/(1.0f+expf(-s));
    }
}

// K8v3: s_att via c-sum pushed inward (no x1c read).
__global__ __launch_bounds__(256) void k8_satt3(
    const float* __restrict__ xm, const float* __restrict__ A,
    const float* __restrict__ catt, const float* __restrict__ x3bar,
    const float* __restrict__ w4, const float* __restrict__ b4,
    const float* __restrict__ wsp, const float* __restrict__ bsp,
    float* __restrict__ satt)
{
    __shared__ __align__(16) float xml[REL_*VV_];  // 20KB
    __shared__ __align__(16) float xbl[OUT_*V_];   // 6.4KB
    __shared__ float Al[VV_];
    __shared__ float w4l[OUT_*REL_];
    __shared__ float scl[OUT_];
    __shared__ float Wl[REL_*V_];
    __shared__ float Yl[V_];
    __shared__ float red[OUT_];
    int n = blockIdx.x, tid = threadIdx.x;
    for (int e=tid; e<1250; e+=256)
        ((float4*)xml)[e] = ((const float4*)(xm + (size_t)n*REL_*VV_))[e];
    for (int e=tid; e<400; e+=256)
        ((float4*)xbl)[e] = ((const float4*)(x3bar + (size_t)n*OUT_*V_))[e];
    for (int e=tid; e<VV_; e+=256) Al[e] = A[e];
    for (int e=tid; e<OUT_*REL_; e+=256) w4l[e] = w4[e];
    if (tid < OUT_) scl[tid] = wsp[tid]*catt[n*OUT_+tid];
    __syncthreads();
    if (tid < REL_*V_){
        int r = tid/V_, v = tid%V_;
        float s = 0.f;
        for (int c=0;c<OUT_;++c) s = fmaf(scl[c]*w4l[c*REL_+r], xbl[c*V_+v], s);
        Wl[tid] = s;
    } else if (tid < REL_*V_ + V_){
        int v = tid - REL_*V_;
        float s = 0.f;
        for (int c=0;c<OUT_;++c) s = fmaf(scl[c], xbl[c*V_+v], s);
        Yl[v] = s;
    }
    __syncthreads();
    if (tid < OUT_){
        float s1 = 0.f;
        #pragma unroll
        for (int v=0;v<V_;++v) s1 += xbl[tid*V_+v];
        red[tid] = scl[tid]*b4[tid]*s1;
    }
    __syncthreads();
    if (tid < V_){
        int u = tid;
        float acc = 0.f;
        #pragma unroll
        for (int r=0;r<REL_;++r){
            const float* xr = xml + r*VV_ + u*V_;
            const float* wr = Wl + r*V_;
            #pragma unroll
            for (int v=0;v<V_;++v) acc = fmaf(xr[v], wr[v], acc);
        }
        #pragma unroll
        for (int v=0;v<V_;++v) acc = fmaf(Al[u*V_+v], Yl[v], acc);
        float beta = 0.f;
        for (int c=0;c<OUT_;++c) beta += red[c];
        satt[n*V_+u] = 1.0f/(1.0f+expf(-(bsp[0]+acc+beta)));
    }
}

// Kcomb3: per (n,c): comb[t,w] = sum_u x3[t,u]*M[w,u], M built on the fly.
__global__ __launch_bounds__(256) void k_comb3(
    const bf16* __restrict__ x3h,
    const float* __restrict__ att8, const float* __restrict__ xm,
    const float* __restrict__ A,
    const float* __restrict__ watt, const float* __restrict__ batt,
    const float* __restrict__ w4, const float* __restrict__ b4,
    const float* __restrict__ catt, const float* __restrict__ satt,
    bf16* __restrict__ combh)
{
    __shared__ __align__(16) unsigned short x3s[TV_];   // 6.4KB
    __shared__ float Ml[VV_];
    __shared__ float sl[V_];
    __shared__ __align__(16) unsigned short cst[TV_];   // 6.4KB
    int bid = blockIdx.x;   // n*OUT + c
    int n = bid >> 6, c = bid & 63;
    int tid = threadIdx.x;
    for (int e = tid; e < 400; e += 256)
        ((uint4*)x3s)[e] = ((const uint4*)(x3h + (size_t)bid*TV_))[e];
    if (tid < V_) sl[tid] = satt[n*V_+tid];
    float ca = catt[bid];
    float w4r[REL_], war[REL_];
    #pragma unroll
    for (int r=0;r<REL_;++r){ w4r[r] = w4[c*REL_+r]; war[r] = watt[c*REL_+r]; }
    float b4c = b4[c], bac = batt[c];
    const float* xmn = xm  + (size_t)n*REL_*VV_;
    const float* a8n = att8 + (size_t)n*REL_*VV_;
    __syncthreads();
    for (int e = tid; e < VV_; e += 256){
        int w = e/V_, u = e%V_;
        float xv = b4c, av = bac;
        #pragma unroll
        for (int r=0;r<REL_;++r){
            xv = fmaf(w4r[r], xmn[r*VV_ + e], xv);
            av = fmaf(war[r], a8n[r*VV_ + u*V_ + w], av);
        }
        Ml[e] = ca*(xv + A[e]) + av*sl[w];
    }
    __syncthreads();
    int vh = tid & 1, tq = tid >> 1;
    int v0 = vh*13, nv = vh ? 12 : 13;
    float x3r[V_];
    #pragma unroll
    for (int u=0;u<V_;++u) x3r[u] = bfs(x3s[tq*V_+u]);
    for (int i=0;i<nv;++i){
        int v = v0+i;
        float s=0.f;
        #pragma unroll
        for (int u=0;u<V_;++u) s = fmaf(Ml[v*V_+u], x3r[u], s);
        bf16 h = f2b(s);
        cst[tq*V_+v] = *(unsigned short*)&h;
    }
    __syncthreads();
    for (int e = tid; e < 400; e += 256)
        ((uint4*)(combh + (size_t)bid*TV_))[e] = ((const uint4*)cst)[e];
}

// K10f7: R4 two-round structure, 512-thread blocks, wave-uniform v-split (acc[13]).
__global__ __launch_bounds__(512) void k10_final7(
    const float* __restrict__ x11f, const float* __restrict__ x22f,
    const bf16* __restrict__ x3h, const bf16* __restrict__ combh,
    const float* __restrict__ beita, float* __restrict__ out)
{
    __shared__ __align__(16) char stg[25600];                 // phase1: l11|l22 ; phase2: staging
    __shared__ __align__(16) unsigned short xtl[TT2*V_*XTP3]; // 16KB
    int bid = blockIdx.x;              // n*16 + tt
    int n = bid >> 4, tt = bid & 15;
    int t0 = tt * TT2;
    int tid = threadIdx.x;
    float* l11 = (float*)stg;          // [8][8][25]
    float* l22 = (float*)(stg + 6400);
    for (int e = tid; e < 400; e += 512){
        int r = e / 50, rem = e % 50;
        ((float4*)l11)[e] = ((const float4*)(x11f + (size_t)(n*REL_+r)*TV_ + t0*V_))[rem];
        ((float4*)l22)[e] = ((const float4*)(x22f + (size_t)(n*REL_+r)*TV_ + t0*V_))[rem];
    }
    __syncthreads();
    for (int e = tid; e < TT2*VV_; e += 512){
        int ti = e / VV_, uv = e % VV_;
        int u = uv / V_, v = uv % V_;
        float s = 0.f;
        #pragma unroll
        for (int r = 0; r < REL_; ++r)
            s = fmaf(l11[r*200 + ti*V_ + u], l22[r*200 + ti*V_ + v], s);
        bf16 h = f2b(ftanh(s * 0.125f));
        xtl[ti*(V_*XTP3) + u*XTP3 + v] = *(unsigned short*)&h;
    }
    float bt = beita[0];
    int vh = tid >> 8;                 // wave-uniform: waves 0-3 -> 0, 4-7 -> 1
    int c_local = (tid >> 3) & 31;
    int ti = tid & 7;
    for (int cr = 0; cr < 2; ++cr){
        int c0 = cr*32;
        __syncthreads();   // xtl ready (cr=0) / prev store done (cr=1)
        for (int e = tid; e < 1600; e += 512){
            int cl = e / 50, w = e % 50;
            size_t base = (size_t)(n*OUT_ + c0 + cl)*TV_ + (size_t)t0*V_;
            uint4 p = (w < 25) ? ((const uint4*)(combh + base))[w]
                               : ((const uint4*)(x3h  + base))[w-25];
            *(uint4*)(stg + cl*800 + (w<25 ? w*16 : 400 + (w-25)*16)) = p;
        }
        __syncthreads();
        const unsigned short* x3row = (const unsigned short*)(stg + c_local*800 + 400) + ti*V_;
        float acc[13];
        #pragma unroll
        for (int j=0;j<13;++j) acc[j]=0.f;
        int base_s = ti*(V_*XTP3) + vh*12;   // even short index -> uint-aligned
        #pragma unroll
        for (int u=0;u<V_;++u){
            float xa = bfs(x3row[u]);        // broadcast within vh pair
            const uint* xr = (const uint*)(xtl + base_s + u*XTP3);
            uint R[7];
            #pragma unroll
            for (int k=0;k<7;++k) R[k] = xr[k];
            if (vh == 0){
                #pragma unroll
                for (int k=0;k<6;++k){
                    acc[2*k]   = fmaf(xa, bfu(R[k]), acc[2*k]);
                    acc[2*k+1] = fmaf(xa, bfh(R[k]), acc[2*k+1]);
                }
                acc[12] = fmaf(xa, bfu(R[6]), acc[12]);
            } else {
                acc[0] = fmaf(xa, bfh(R[0]), acc[0]);
                #pragma unroll
                for (int k=1;k<6;++k){
                    acc[2*k-1] = fmaf(xa, bfu(R[k]), acc[2*k-1]);
                    acc[2*k]   = fmaf(xa, bfh(R[k]), acc[2*k]);
                }
                acc[11] = fmaf(xa, bfu(R[6]), acc[11]);
            }
        }
        const unsigned short* cmbrow =
            (const unsigned short*)(stg + c_local*800) + ti*V_ + vh*13;
        if (vh == 0){
            #pragma unroll
            for (int j=0;j<13;++j) acc[j] = fmaf(bt, acc[j], bfs(cmbrow[j]));
        } else {
            #pragma unroll
            for (int j=0;j<12;++j) acc[j] = fmaf(bt, acc[j], bfs(cmbrow[j]));
        }
        __syncthreads();   // all stage reads done before overwrite
        float* orow = (float*)(stg + c_local*800 + ti*100) + vh*13;
        if (vh == 0){
            #pragma unroll
            for (int j=0;j<13;++j) orow[j] = acc[j];
        } else {
            #pragma unroll
            for (int j=0;j<12;++j) orow[j] = acc[j];
        }
        __syncthreads();
        for (int e = tid; e < 1600; e += 512){
            int cl = e / 50, q = e % 50;
            *(float4*)(out + (size_t)(n*OUT_ + c0 + cl)*TV_ + (size_t)t0*V_ + q*4) =
                *(const float4*)(stg + cl*800 + q*16);
        }
    }
}

extern "C" void kernel_launch(void* const* d_in, const int* in_sizes, int n_in,
                              void* d_out, int out_size, void* d_ws, size_t ws_size,
                              hipStream_t stream)
{
    const float* x    = (const float*)d_in[0];
    const float* A    = (const float*)d_in[1];
    const float* w1   = (const float*)d_in[2];  const float* b1  = (const float*)d_in[3];
    const float* w2   = (const float*)d_in[4];  const float* b2  = (const float*)d_in[5];
    const float* w11  = (const float*)d_in[6];  const float* b11 = (const float*)d_in[7];
    const float* w22  = (const float*)d_in[8];  const float* b22 = (const float*)d_in[9];
    const float* w3   = (const float*)d_in[10]; const float* b3  = (const float*)d_in[11];
    const float* w4   = (const float*)d_in[12]; const float* b4  = (const float*)d_in[13];
    const float* watt = (const float*)d_in[14]; const float* batt= (const float*)d_in[15];
    const float* w5   = (const float*)d_in[16]; const float* b5  = (const float*)d_in[17];
    const float* wc1  = (const float*)d_in[18]; const float* bc1 = (const float*)d_in[19];
    const float* bng  = (const float*)d_in[20]; const float* bnb = (const float*)d_in[21];
    const float* bnm  = (const float*)d_in[22]; const float* bnv = (const float*)d_in[23];
    const float* wc2  = (const float*)d_in[24]; const float* bc2 = (const float*)d_in[25];
    const float* wsp  = (const float*)d_in[26]; const float* bsp = (const float*)d_in[27];
    const float* beita= (const float*)d_in[28];
    const int*  alpha = (const int*)d_in[29];
    float* out = (float*)d_out;

    char* wsb = (char*)d_ws;
    size_t off = 0;
    auto alloc = [&](size_t bytes)->char*{
        char* p = wsb + off;
        off += (bytes + 255) & ~(size_t)255;
        return p;
    };
    float* x1f   = (float*)alloc((size_t)N_*REL_*TV_*4);
    float* x2f   = (float*)alloc((size_t)N_*REL_*TV_*4);
    float* x11f  = (float*)alloc((size_t)N_*REL_*TV_*4);
    float* x22f  = (float*)alloc((size_t)N_*REL_*TV_*4);
    bf16*  x3h   = (bf16*) alloc((size_t)N_*OUT_*TV_*2);
    bf16*  combh = (bf16*) alloc((size_t)N_*OUT_*TV_*2);
    float* att8  = (float*)alloc((size_t)N_*REL_*VV_*4);
    float* xm    = (float*)alloc((size_t)N_*REL_*VV_*4);
    float* x3bar = (float*)alloc((size_t)N_*OUT_*V_*4);
    float* catt  = (float*)alloc((size_t)N_*OUT_*4);
    float* satt  = (float*)alloc((size_t)N_*V_*4);
    float* WTgP  = (float*)alloc((size_t)C_*16*8*4);
    float* Bg    = (float*)alloc((size_t)96*4);
    (void)ws_size; (void)n_in; (void)in_sizes; (void)out_size;

    k0_prep<<<1, 256, 0, stream>>>(w1,b1, w2,b2, w11,b11, w22,b22, w3,b3, WTgP, Bg);
    k1_convs<<<N_*50, 256, 0, stream>>>(x, WTgP, Bg, x1f, x2f, x11f, x22f, x3h);
    k_x3bar2<<<N_*OUT_, 256, 0, stream>>>(x3h, x3bar);
    k3_att8_xm<<<N_*REL_, 256, 0, stream>>>(x1f, x2f, w5, b5, alpha, att8, xm);
    k6_chatt2<<<N_, 256, 0, stream>>>(att8, x3bar, watt, batt,
                                      wc1, bc1, bng, bnb, bnm, bnv, wc2, bc2, catt);
    k8_satt3<<<N_, 256, 0, stream>>>(xm, A, catt, x3bar, w4, b4, wsp, bsp, satt);
    k_comb3<<<N_*OUT_, 256, 0, stream>>>(x3h, att8, xm, A, watt, batt, w4, b4,
                                         catt, satt, combh);
    k10_final7<<<N_*16, 512, 0, stream>>>(x11f, x22f, x3h, combh, beita, out);
}

// Round 14
// 166.144 us; speedup vs baseline: 1.0995x; 1.0995x over previous
//
#include <hip/hip_runtime.h>
#include <hip/hip_bf16.h>
#include <math.h>

#define N_   64
#define C_   64
#define T_   128
#define V_   25
#define OUT_ 64
#define REL_ 8
#define MID_ 32
#define TV_  (T_*V_)   // 3200
#define VV_  (V_*V_)   // 625
#define TT2  8         // t-tile for fused temporal kernel
#define XTP3 40        // xtl row pad in shorts (80B: 16B-aligned rows)

typedef __hip_bfloat16 bf16;
typedef unsigned int uint;
__device__ __forceinline__ float b2f(bf16 x){ return __bfloat162float(x); }
__device__ __forceinline__ bf16  f2b(float x){ return __float2bfloat16(x); }
__device__ __forceinline__ float bfu(uint u){ return __uint_as_float(u<<16); }
__device__ __forceinline__ float bfh(uint u){ return __uint_as_float(u&0xffff0000u); }
__device__ __forceinline__ float bfs(unsigned short s){ return __uint_as_float(((uint)s)<<16); }

// fast tanh: clamp + (e^{2x}-1)/(e^{2x}+1); abs err ~1e-6, threshold 1.9e-2.
__device__ __forceinline__ float ftanh(float x){
    float cx = fminf(fmaxf(x, -15.f), 15.f);
    float e  = __expf(2.0f*cx);
    return (e - 1.0f) / (e + 1.0f);
}

// LESSONS (measured, R4-R13):
//  * launch_bounds min-waves caps -> VGPR spill -> GBs scratch traffic (R6-R8). Banned.
//  * k10 acc[25]->acc[13] wave-uniform v-split: 87->~53us (R12). Natural VGPR
//    reduction only.
//  * R13: moving the 32KB BROADCAST weight table to global/L1 regressed
//    (L1 thrashed by x stream -> L2-latency-bound, VALUBusy 25%). Broadcast
//    tables -> LDS; STREAMING operand (x) -> global direct (L1 absorbs the
//    4x intra-block reuse). This round k1 keeps weights in LDS, x global.
//  * attc/x1c materialization eliminated algebraically (R10).

// K0: transpose weights into WTg[c][96] + biases Bg[96]
__global__ __launch_bounds__(256) void k0_prep(
    const float* __restrict__ w1, const float* __restrict__ b1,
    const float* __restrict__ w2, const float* __restrict__ b2,
    const float* __restrict__ w11, const float* __restrict__ b11,
    const float* __restrict__ w22, const float* __restrict__ b22,
    const float* __restrict__ w3, const float* __restrict__ b3,
    float* __restrict__ WTg, float* __restrict__ Bg)
{
    int tid = threadIdx.x;
    for (int e = tid; e < 96*C_; e += 256){
        int o = e / C_, c = e % C_;
        float w;
        if      (o < 8)  w = w1[o*C_+c];
        else if (o < 16) w = w2[(o-8)*C_+c];
        else if (o < 24) w = w11[(o-16)*C_+c];
        else if (o < 32) w = w22[(o-24)*C_+c];
        else             w = w3[(o-32)*C_+c];
        WTg[c*96 + o] = w;
    }
    if (tid < 96){
        int o = tid; float bb;
        if      (o < 8)  bb = b1[o];
        else if (o < 16) bb = b2[o-8];
        else if (o < 24) bb = b11[o-16];
        else if (o < 32) bb = b22[o-24];
        else             bb = b3[o-32];
        Bg[o] = bb;
    }
}

// K1: five 1x1 convs. Weights in LDS (24KB broadcast table); x read DIRECT
// from global (stream-once, L1 serves intra-block reuse). LDS 24.6KB ->
// ~6 blocks/CU -> ~24 waves/CU.
__global__ __launch_bounds__(256) void k1_convs(
    const float* __restrict__ x,
    const float* __restrict__ WTg, const float* __restrict__ Bg,
    float* __restrict__ x1f, float* __restrict__ x2f,
    float* __restrict__ x11f, float* __restrict__ x22f,
    bf16* __restrict__ x3h)
{
    __shared__ __align__(16) float WTl[C_*96];   // 24KB
    __shared__ float Bl[96];
    int bid = blockIdx.x;
    int n = bid / 50, jt = bid % 50;
    int j0 = jt * 64;
    int tid = threadIdx.x;
    for (int e = tid; e < 1536; e += 256)
        ((float4*)WTl)[e] = ((const float4*)WTg)[e];
    if (tid < 96) Bl[tid] = Bg[tid];
    __syncthreads();

    int og = tid >> 4;
    int jg = tid & 15;
    int o0 = og*6, jj = jg*4;
    const float* xp = x + (size_t)n*C_*TV_ + j0 + jj;
    float acc[6][4];
    #pragma unroll
    for (int i=0;i<6;i++){
        float b = Bl[o0+i];
        #pragma unroll
        for (int q=0;q<4;q++) acc[i][q] = b;
    }
    #pragma unroll 8
    for (int c = 0; c < C_; ++c){
        float4 xv = *(const float4*)(xp + (size_t)c*TV_);
        float w0=WTl[c*96+o0+0], w1_=WTl[c*96+o0+1], w2_=WTl[c*96+o0+2];
        float w3_=WTl[c*96+o0+3], w4_=WTl[c*96+o0+4], w5_=WTl[c*96+o0+5];
        acc[0][0]=fmaf(w0,xv.x,acc[0][0]); acc[0][1]=fmaf(w0,xv.y,acc[0][1]);
        acc[0][2]=fmaf(w0,xv.z,acc[0][2]); acc[0][3]=fmaf(w0,xv.w,acc[0][3]);
        acc[1][0]=fmaf(w1_,xv.x,acc[1][0]); acc[1][1]=fmaf(w1_,xv.y,acc[1][1]);
        acc[1][2]=fmaf(w1_,xv.z,acc[1][2]); acc[1][3]=fmaf(w1_,xv.w,acc[1][3]);
        acc[2][0]=fmaf(w2_,xv.x,acc[2][0]); acc[2][1]=fmaf(w2_,xv.y,acc[2][1]);
        acc[2][2]=fmaf(w2_,xv.z,acc[2][2]); acc[2][3]=fmaf(w2_,xv.w,acc[2][3]);
        acc[3][0]=fmaf(w3_,xv.x,acc[3][0]); acc[3][1]=fmaf(w3_,xv.y,acc[3][1]);
        acc[3][2]=fmaf(w3_,xv.z,acc[3][2]); acc[3][3]=fmaf(w3_,xv.w,acc[3][3]);
        acc[4][0]=fmaf(w4_,xv.x,acc[4][0]); acc[4][1]=fmaf(w4_,xv.y,acc[4][1]);
        acc[4][2]=fmaf(w4_,xv.z,acc[4][2]); acc[4][3]=fmaf(w4_,xv.w,acc[4][3]);
        acc[5][0]=fmaf(w5_,xv.x,acc[5][0]); acc[5][1]=fmaf(w5_,xv.y,acc[5][1]);
        acc[5][2]=fmaf(w5_,xv.z,acc[5][2]); acc[5][3]=fmaf(w5_,xv.w,acc[5][3]);
    }
    int pos = j0 + jj;
    #pragma unroll
    for (int i=0;i<6;i++){
        int o = o0 + i;
        float4 v = make_float4(acc[i][0], acc[i][1], acc[i][2], acc[i][3]);
        if      (o < 8)  *(float4*)&x1f [(size_t)(n*REL_+o)     *TV_ + pos] = v;
        else if (o < 16) *(float4*)&x2f [(size_t)(n*REL_+(o-8)) *TV_ + pos] = v;
        else if (o < 24) *(float4*)&x11f[(size_t)(n*REL_+(o-16))*TV_ + pos] = v;
        else if (o < 32) *(float4*)&x22f[(size_t)(n*REL_+(o-24))*TV_ + pos] = v;
        else {
            bf16 h0=f2b(v.x), h1=f2b(v.y), h2=f2b(v.z), h3=f2b(v.w);
            ushort4 pk;
            pk.x = *(unsigned short*)&h0; pk.y = *(unsigned short*)&h1;
            pk.z = *(unsigned short*)&h2; pk.w = *(unsigned short*)&h3;
            *(ushort4*)&x3h[(size_t)(n*OUT_+(o-32))*TV_ + pos] = pk;
        }
    }
}

// Kx3bar v2: coalesced uint4 staging -> LDS fp32 -> two-level reduce.
__global__ __launch_bounds__(256) void k_x3bar2(const bf16* __restrict__ x3h,
                                                float* __restrict__ x3bar)
{
    __shared__ __align__(16) float xf[TV_];   // 12.8KB
    __shared__ float red[V_*8];
    int bid = blockIdx.x;   // n*OUT + c
    int tid = threadIdx.x;
    for (int e = tid; e < 400; e += 256){
        uint4 p = ((const uint4*)(x3h + (size_t)bid*TV_))[e];
        float* d = xf + e*8;
        d[0]=bfu(p.x); d[1]=bfh(p.x); d[2]=bfu(p.y); d[3]=bfh(p.y);
        d[4]=bfu(p.z); d[5]=bfh(p.z); d[6]=bfu(p.w); d[7]=bfh(p.w);
    }
    __syncthreads();
    if (tid < 200){
        int v = tid % V_, g = tid / V_;
        float s = 0.f;
        #pragma unroll
        for (int k=0;k<16;++k) s += xf[(g*16+k)*V_ + v];
        red[g*V_+v] = s;
    }
    __syncthreads();
    if (tid < V_){
        float s = 0.f;
        #pragma unroll
        for (int g=0; g<8; ++g) s += red[g*V_+tid];
        x3bar[(size_t)bid*V_+tid] = s * (1.0f/T_);
    }
}

// K3: att8 = tanh(x1^T x2 / T);  xm = tanh(w5_0*mean_res + w5_1*max_res + b5)*alpha
__global__ __launch_bounds__(256) void k3_att8_xm(
    const float* __restrict__ x1f, const float* __restrict__ x2f,
    const float* __restrict__ w5, const float* __restrict__ b5,
    const int* __restrict__ alpha,
    float* __restrict__ att8, float* __restrict__ xm)
{
    __shared__ __align__(16) float l1[TV_], l2[TV_];
    __shared__ float mu1l[V_], mu2l[V_], m1l[V_], m2l[V_];
    int bid = blockIdx.x;      // n*REL + r
    int tid = threadIdx.x;
    int r = bid % REL_;
    for (int e = tid; e < 800; e += 256){
        ((float4*)l1)[e] = ((const float4*)(x1f + (size_t)bid*TV_))[e];
        ((float4*)l2)[e] = ((const float4*)(x2f + (size_t)bid*TV_))[e];
    }
    __syncthreads();
    if (tid < 50){
        int v = tid % V_;
        const float* L = (tid < V_) ? l1 : l2;
        float s=0.f, mm=-1e30f;
        for (int t=0;t<T_;++t){
            float a = L[t*V_+v];
            s += a; mm = fmaxf(mm, a);
        }
        if (tid < V_){ mu1l[v]=s*(1.0f/T_); m1l[v]=mm; }
        else         { mu2l[v]=s*(1.0f/T_); m2l[v]=mm; }
    }
    __syncthreads();
    float w50=w5[r*2+0], w51=w5[r*2+1], b5r=b5[r];
    float af = (float)alpha[0];
    for (int idx=tid; idx<VV_; idx+=256){
        int u = idx/V_, v = idx%V_;
        float s=0.f;
        for (int t=0;t<T_;++t) s = fmaf(l1[t*V_+u], l2[t*V_+v], s);
        att8[(size_t)bid*VV_+idx] = ftanh(s*(1.0f/T_));
        float mr = mu1l[u]-mu2l[v];
        float xr = m1l[u]-m2l[v];
        xm[(size_t)bid*VV_+idx] = ftanh(fmaf(w50,mr,fmaf(w51,xr,b5r))) * af;
    }
}

// K6v2: channel attention; no attc materialization.
__global__ __launch_bounds__(256) void k6_chatt2(
    const float* __restrict__ att8, const float* __restrict__ x3bar,
    const float* __restrict__ watt, const float* __restrict__ batt,
    const float* __restrict__ wc1, const float* __restrict__ bc1,
    const float* __restrict__ bng, const float* __restrict__ bnb,
    const float* __restrict__ bnm, const float* __restrict__ bnv,
    const float* __restrict__ wc2, const float* __restrict__ bc2,
    float* __restrict__ catt)
{
    __shared__ float rs8[REL_*V_];
    __shared__ float gl[OUT_];
    __shared__ float hl[MID_];
    int n = blockIdx.x, tid = threadIdx.x;
    if (tid < REL_*V_){
        int r = tid / V_, u = tid % V_;
        const float* p = att8 + (size_t)(n*REL_+r)*VV_ + u*V_;
        float s = 0.f;
        #pragma unroll
        for (int v=0;v<V_;++v) s += p[v];
        rs8[tid] = s;
    }
    __syncthreads();
    if (tid < OUT_){
        int c = tid;
        const float* xb = x3bar + (size_t)(n*OUT_+c)*V_;
        float xbr[V_], sb = 0.f;
        #pragma unroll
        for (int u=0;u<V_;++u){ xbr[u]=xb[u]; sb += xbr[u]; }
        float s = 0.f;
        #pragma unroll
        for (int r=0;r<REL_;++r){
            float d = 0.f;
            #pragma unroll
            for (int u=0;u<V_;++u) d = fmaf(xbr[u], rs8[r*V_+u], d);
            s = fmaf(watt[c*REL_+r], d, s);
        }
        gl[c] = (s + (float)V_*batt[c]*sb) * (1.0f/(float)V_);
    }
    __syncthreads();
    if (tid < MID_){
        float h = bc1[tid];
        for (int c=0;c<OUT_;++c) h = fmaf(wc1[tid*OUT_+c], gl[c], h);
        h = (h - bnm[tid]) * bng[tid] * rsqrtf(bnv[tid] + 1e-5f) + bnb[tid];
        h = 0.5f*h*(1.0f+erff(h*0.70710678118654752f));
        hl[tid]=h;
    }
    __syncthreads();
    if (tid < OUT_){
        float s = bc2[tid];
        for (int m=0;m<MID_;++m) s = fmaf(wc2[tid*MID_+m], hl[m], s);
        catt[n*OUT_+tid] = 1.0f/(1.0f+expf(-s));
    }
}

// K8v3: s_att via c-sum pushed inward (no x1c read).
__global__ __launch_bounds__(256) void k8_satt3(
    const float* __restrict__ xm, const float* __restrict__ A,
    const float* __restrict__ catt, const float* __restrict__ x3bar,
    const float* __restrict__ w4, const float* __restrict__ b4,
    const float* __restrict__ wsp, const float* __restrict__ bsp,
    float* __restrict__ satt)
{
    __shared__ __align__(16) float xml[REL_*VV_];  // 20KB
    __shared__ __align__(16) float xbl[OUT_*V_];   // 6.4KB
    __shared__ float Al[VV_];
    __shared__ float w4l[OUT_*REL_];
    __shared__ float scl[OUT_];
    __shared__ float Wl[REL_*V_];
    __shared__ float Yl[V_];
    __shared__ float red[OUT_];
    int n = blockIdx.x, tid = threadIdx.x;
    for (int e=tid; e<1250; e+=256)
        ((float4*)xml)[e] = ((const float4*)(xm + (size_t)n*REL_*VV_))[e];
    for (int e=tid; e<400; e+=256)
        ((float4*)xbl)[e] = ((const float4*)(x3bar + (size_t)n*OUT_*V_))[e];
    for (int e=tid; e<VV_; e+=256) Al[e] = A[e];
    for (int e=tid; e<OUT_*REL_; e+=256) w4l[e] = w4[e];
    if (tid < OUT_) scl[tid] = wsp[tid]*catt[n*OUT_+tid];
    __syncthreads();
    if (tid < REL_*V_){
        int r = tid/V_, v = tid%V_;
        float s = 0.f;
        for (int c=0;c<OUT_;++c) s = fmaf(scl[c]*w4l[c*REL_+r], xbl[c*V_+v], s);
        Wl[tid] = s;
    } else if (tid < REL_*V_ + V_){
        int v = tid - REL_*V_;
        float s = 0.f;
        for (int c=0;c<OUT_;++c) s = fmaf(scl[c], xbl[c*V_+v], s);
        Yl[v] = s;
    }
    __syncthreads();
    if (tid < OUT_){
        float s1 = 0.f;
        #pragma unroll
        for (int v=0;v<V_;++v) s1 += xbl[tid*V_+v];
        red[tid] = scl[tid]*b4[tid]*s1;
    }
    __syncthreads();
    if (tid < V_){
        int u = tid;
        float acc = 0.f;
        #pragma unroll
        for (int r=0;r<REL_;++r){
            const float* xr = xml + r*VV_ + u*V_;
            const float* wr = Wl + r*V_;
            #pragma unroll
            for (int v=0;v<V_;++v) acc = fmaf(xr[v], wr[v], acc);
        }
        #pragma unroll
        for (int v=0;v<V_;++v) acc = fmaf(Al[u*V_+v], Yl[v], acc);
        float beta = 0.f;
        for (int c=0;c<OUT_;++c) beta += red[c];
        satt[n*V_+u] = 1.0f/(1.0f+expf(-(bsp[0]+acc+beta)));
    }
}

// Kcomb3: per (n,c): comb[t,w] = sum_u x3[t,u]*M[w,u], M built on the fly.
__global__ __launch_bounds__(256) void k_comb3(
    const bf16* __restrict__ x3h,
    const float* __restrict__ att8, const float* __restrict__ xm,
    const float* __restrict__ A,
    const float* __restrict__ watt, const float* __restrict__ batt,
    const float* __restrict__ w4, const float* __restrict__ b4,
    const float* __restrict__ catt, const float* __restrict__ satt,
    bf16* __restrict__ combh)
{
    __shared__ __align__(16) unsigned short x3s[TV_];   // 6.4KB
    __shared__ float Ml[VV_];
    __shared__ float sl[V_];
    __shared__ __align__(16) unsigned short cst[TV_];   // 6.4KB
    int bid = blockIdx.x;   // n*OUT + c
    int n = bid >> 6, c = bid & 63;
    int tid = threadIdx.x;
    for (int e = tid; e < 400; e += 256)
        ((uint4*)x3s)[e] = ((const uint4*)(x3h + (size_t)bid*TV_))[e];
    if (tid < V_) sl[tid] = satt[n*V_+tid];
    float ca = catt[bid];
    float w4r[REL_], war[REL_];
    #pragma unroll
    for (int r=0;r<REL_;++r){ w4r[r] = w4[c*REL_+r]; war[r] = watt[c*REL_+r]; }
    float b4c = b4[c], bac = batt[c];
    const float* xmn = xm  + (size_t)n*REL_*VV_;
    const float* a8n = att8 + (size_t)n*REL_*VV_;
    __syncthreads();
    for (int e = tid; e < VV_; e += 256){
        int w = e/V_, u = e%V_;
        float xv = b4c, av = bac;
        #pragma unroll
        for (int r=0;r<REL_;++r){
            xv = fmaf(w4r[r], xmn[r*VV_ + e], xv);
            av = fmaf(war[r], a8n[r*VV_ + u*V_ + w], av);
        }
        Ml[e] = ca*(xv + A[e]) + av*sl[w];
    }
    __syncthreads();
    int vh = tid & 1, tq = tid >> 1;
    int v0 = vh*13, nv = vh ? 12 : 13;
    float x3r[V_];
    #pragma unroll
    for (int u=0;u<V_;++u) x3r[u] = bfs(x3s[tq*V_+u]);
    for (int i=0;i<nv;++i){
        int v = v0+i;
        float s=0.f;
        #pragma unroll
        for (int u=0;u<V_;++u) s = fmaf(Ml[v*V_+u], x3r[u], s);
        bf16 h = f2b(s);
        cst[tq*V_+v] = *(unsigned short*)&h;
    }
    __syncthreads();
    for (int e = tid; e < 400; e += 256)
        ((uint4*)(combh + (size_t)bid*TV_))[e] = ((const uint4*)cst)[e];
}

// K10f7: R4 two-round structure, 512-thread blocks, wave-uniform v-split (acc[13]).
__global__ __launch_bounds__(512) void k10_final7(
    const float* __restrict__ x11f, const float* __restrict__ x22f,
    const bf16* __restrict__ x3h, const bf16* __restrict__ combh,
    const float* __restrict__ beita, float* __restrict__ out)
{
    __shared__ __align__(16) char stg[25600];                 // phase1: l11|l22 ; phase2: staging
    __shared__ __align__(16) unsigned short xtl[TT2*V_*XTP3]; // 16KB
    int bid = blockIdx.x;              // n*16 + tt
    int n = bid >> 4, tt = bid & 15;
    int t0 = tt * TT2;
    int tid = threadIdx.x;
    float* l11 = (float*)stg;          // [8][8][25]
    float* l22 = (float*)(stg + 6400);
    for (int e = tid; e < 400; e += 512){
        int r = e / 50, rem = e % 50;
        ((float4*)l11)[e] = ((const float4*)(x11f + (size_t)(n*REL_+r)*TV_ + t0*V_))[rem];
        ((float4*)l22)[e] = ((const float4*)(x22f + (size_t)(n*REL_+r)*TV_ + t0*V_))[rem];
    }
    __syncthreads();
    for (int e = tid; e < TT2*VV_; e += 512){
        int ti = e / VV_, uv = e % VV_;
        int u = uv / V_, v = uv % V_;
        float s = 0.f;
        #pragma unroll
        for (int r = 0; r < REL_; ++r)
            s = fmaf(l11[r*200 + ti*V_ + u], l22[r*200 + ti*V_ + v], s);
        bf16 h = f2b(ftanh(s * 0.125f));
        xtl[ti*(V_*XTP3) + u*XTP3 + v] = *(unsigned short*)&h;
    }
    float bt = beita[0];
    int vh = tid >> 8;                 // wave-uniform: waves 0-3 -> 0, 4-7 -> 1
    int c_local = (tid >> 3) & 31;
    int ti = tid & 7;
    for (int cr = 0; cr < 2; ++cr){
        int c0 = cr*32;
        __syncthreads();   // xtl ready (cr=0) / prev store done (cr=1)
        for (int e = tid; e < 1600; e += 512){
            int cl = e / 50, w = e % 50;
            size_t base = (size_t)(n*OUT_ + c0 + cl)*TV_ + (size_t)t0*V_;
            uint4 p = (w < 25) ? ((const uint4*)(combh + base))[w]
                               : ((const uint4*)(x3h  + base))[w-25];
            *(uint4*)(stg + cl*800 + (w<25 ? w*16 : 400 + (w-25)*16)) = p;
        }
        __syncthreads();
        const unsigned short* x3row = (const unsigned short*)(stg + c_local*800 + 400) + ti*V_;
        float acc[13];
        #pragma unroll
        for (int j=0;j<13;++j) acc[j]=0.f;
        int base_s = ti*(V_*XTP3) + vh*12;   // even short index -> uint-aligned
        #pragma unroll
        for (int u=0;u<V_;++u){
            float xa = bfs(x3row[u]);        // broadcast within vh pair
            const uint* xr = (const uint*)(xtl + base_s + u*XTP3);
            uint R[7];
            #pragma unroll
            for (int k=0;k<7;++k) R[k] = xr[k];
            if (vh == 0){
                #pragma unroll
                for (int k=0;k<6;++k){
                    acc[2*k]   = fmaf(xa, bfu(R[k]), acc[2*k]);
                    acc[2*k+1] = fmaf(xa, bfh(R[k]), acc[2*k+1]);
                }
                acc[12] = fmaf(xa, bfu(R[6]), acc[12]);
            } else {
                acc[0] = fmaf(xa, bfh(R[0]), acc[0]);
                #pragma unroll
                for (int k=1;k<6;++k){
                    acc[2*k-1] = fmaf(xa, bfu(R[k]), acc[2*k-1]);
                    acc[2*k]   = fmaf(xa, bfh(R[k]), acc[2*k]);
                }
                acc[11] = fmaf(xa, bfu(R[6]), acc[11]);
            }
        }
        const unsigned short* cmbrow =
            (const unsigned short*)(stg + c_local*800) + ti*V_ + vh*13;
        if (vh == 0){
            #pragma unroll
            for (int j=0;j<13;++j) acc[j] = fmaf(bt, acc[j], bfs(cmbrow[j]));
        } else {
            #pragma unroll
            for (int j=0;j<12;++j) acc[j] = fmaf(bt, acc[j], bfs(cmbrow[j]));
        }
        __syncthreads();   // all stage reads done before overwrite
        float* orow = (float*)(stg + c_local*800 + ti*100) + vh*13;
        if (vh == 0){
            #pragma unroll
            for (int j=0;j<13;++j) orow[j] = acc[j];
        } else {
            #pragma unroll
            for (int j=0;j<12;++j) orow[j] = acc[j];
        }
        __syncthreads();
        for (int e = tid; e < 1600; e += 512){
            int cl = e / 50, q = e % 50;
            *(float4*)(out + (size_t)(n*OUT_ + c0 + cl)*TV_ + (size_t)t0*V_ + q*4) =
                *(const float4*)(stg + cl*800 + q*16);
        }
    }
}

extern "C" void kernel_launch(void* const* d_in, const int* in_sizes, int n_in,
                              void* d_out, int out_size, void* d_ws, size_t ws_size,
                              hipStream_t stream)
{
    const float* x    = (const float*)d_in[0];
    const float* A    = (const float*)d_in[1];
    const float* w1   = (const float*)d_in[2];  const float* b1  = (const float*)d_in[3];
    const float* w2   = (const float*)d_in[4];  const float* b2  = (const float*)d_in[5];
    const float* w11  = (const float*)d_in[6];  const float* b11 = (const float*)d_in[7];
    const float* w22  = (const float*)d_in[8];  const float* b22 = (const float*)d_in[9];
    const float* w3   = (const float*)d_in[10]; const float* b3  = (const float*)d_in[11];
    const float* w4   = (const float*)d_in[12]; const float* b4  = (const float*)d_in[13];
    const float* watt = (const float*)d_in[14]; const float* batt= (const float*)d_in[15];
    const float* w5   = (const float*)d_in[16]; const float* b5  = (const float*)d_in[17];
    const float* wc1  = (const float*)d_in[18]; const float* bc1 = (const float*)d_in[19];
    const float* bng  = (const float*)d_in[20]; const float* bnb = (const float*)d_in[21];
    const float* bnm  = (const float*)d_in[22]; const float* bnv = (const float*)d_in[23];
    const float* wc2  = (const float*)d_in[24]; const float* bc2 = (const float*)d_in[25];
    const float* wsp  = (const float*)d_in[26]; const float* bsp = (const float*)d_in[27];
    const float* beita= (const float*)d_in[28];
    const int*  alpha = (const int*)d_in[29];
    float* out = (float*)d_out;

    char* wsb = (char*)d_ws;
    size_t off = 0;
    auto alloc = [&](size_t bytes)->char*{
        char* p = wsb + off;
        off += (bytes + 255) & ~(size_t)255;
        return p;
    };
    float* x1f   = (float*)alloc((size_t)N_*REL_*TV_*4);
    float* x2f   = (float*)alloc((size_t)N_*REL_*TV_*4);
    float* x11f  = (float*)alloc((size_t)N_*REL_*TV_*4);
    float* x22f  = (float*)alloc((size_t)N_*REL_*TV_*4);
    bf16*  x3h   = (bf16*) alloc((size_t)N_*OUT_*TV_*2);
    bf16*  combh = (bf16*) alloc((size_t)N_*OUT_*TV_*2);
    float* att8  = (float*)alloc((size_t)N_*REL_*VV_*4);
    float* xm    = (float*)alloc((size_t)N_*REL_*VV_*4);
    float* x3bar = (float*)alloc((size_t)N_*OUT_*V_*4);
    float* catt  = (float*)alloc((size_t)N_*OUT_*4);
    float* satt  = (float*)alloc((size_t)N_*V_*4);
    float* WTg   = (float*)alloc((size_t)96*C_*4);
    float* Bg    = (float*)alloc((size_t)96*4);
    (void)ws_size; (void)n_in; (void)in_sizes; (void)out_size;

    k0_prep<<<1, 256, 0, stream>>>(w1,b1, w2,b2, w11,b11, w22,b22, w3,b3, WTg, Bg);
    k1_convs<<<N_*50, 256, 0, stream>>>(x, WTg, Bg, x1f, x2f, x11f, x22f, x3h);
    k_x3bar2<<<N_*OUT_, 256, 0, stream>>>(x3h, x3bar);
    k3_att8_xm<<<N_*REL_, 256, 0, stream>>>(x1f, x2f, w5, b5, alpha, att8, xm);
    k6_chatt2<<<N_, 256, 0, stream>>>(att8, x3bar, watt, batt,
                                      wc1, bc1, bng, bnb, bnm, bnv, wc2, bc2, catt);
    k8_satt3<<<N_, 256, 0, stream>>>(xm, A, catt, x3bar, w4, b4, wsp, bsp, satt);
    k_comb3<<<N_*OUT_, 256, 0, stream>>>(x3h, att8, xm, A, watt, batt, w4, b4,
                                         catt, satt, combh);
    k10_final7<<<N_*16, 512, 0, stream>>>(x11f, x22f, x3h, combh, beita, out);
}

// Round 15
// 141.555 us; speedup vs baseline: 1.2905x; 1.1737x over previous
//
#include <hip/hip_runtime.h>
#include <hip/hip_bf16.h>
#include <math.h>

#define N_   64
#define C_   64
#define T_   128
#define V_   25
#define OUT_ 64
#define REL_ 8
#define MID_ 32
#define TV_  (T_*V_)   // 3200
#define VV_  (V_*V_)   // 625
#define TT2  8         // t-tile for fused temporal kernel
#define XTP3 40        // xtl row pad in shorts (80B: 16B-aligned rows)

typedef __hip_bfloat16 bf16;
typedef unsigned int uint;
typedef __attribute__((ext_vector_type(8))) short short8v;   // 8 bf16 (4 VGPR)
typedef __attribute__((ext_vector_type(4))) float float4v;   // MFMA accum
__device__ __forceinline__ float b2f(bf16 x){ return __bfloat162float(x); }
__device__ __forceinline__ bf16  f2b(float x){ return __float2bfloat16(x); }
__device__ __forceinline__ float bfu(uint u){ return __uint_as_float(u<<16); }
__device__ __forceinline__ float bfh(uint u){ return __uint_as_float(u&0xffff0000u); }
__device__ __forceinline__ float bfs(unsigned short s){ return __uint_as_float(((uint)s)<<16); }

// fast tanh: clamp + (e^{2x}-1)/(e^{2x}+1); abs err ~1e-6, threshold 1.9e-2.
__device__ __forceinline__ float ftanh(float x){
    float cx = fminf(fmaxf(x, -15.f), 15.f);
    float e  = __expf(2.0f*cx);
    return (e - 1.0f) / (e + 1.0f);
}

// LESSONS (measured, R4-R14):
//  * launch_bounds min-waves caps -> VGPR spill -> GBs scratch traffic (R6-R8). Banned.
//  * k10 acc[25]->acc[13] wave-uniform v-split: 87->~53us (R12).
//  * k1 scalar-FMA formulation plateaued at 56-72us across LDS/L1 layout
//    shuffles (R12 both-LDS 56-62 best; R13 W-in-L1 regressed; R14 x-global 66).
//    -> R15: MFMA (G10). W/x rounded to bf16 (x3-path already bf16-tolerant).
//  * attc/x1c materialization eliminated algebraically (R10).

// K0: build bf16 A-fragment table WfragUS[mt][kb][lane][e] (lane layout:
// m = mt*16+(lane&15), k = kb*32+(lane>>4)*8+e) + biases Bg[96].
__global__ __launch_bounds__(256) void k0_prep(
    const float* __restrict__ w1, const float* __restrict__ b1,
    const float* __restrict__ w2, const float* __restrict__ b2,
    const float* __restrict__ w11, const float* __restrict__ b11,
    const float* __restrict__ w22, const float* __restrict__ b22,
    const float* __restrict__ w3, const float* __restrict__ b3,
    unsigned short* __restrict__ WfragUS, float* __restrict__ Bg)
{
    int tid = threadIdx.x;
    for (int idx = tid; idx < 6144; idx += 256){
        int e  = idx & 7;
        int ln = (idx >> 3) & 63;
        int kb = (idx >> 9) & 1;
        int mt = idx >> 10;
        int m = mt*16 + (ln & 15);
        int k = kb*32 + ((ln >> 4) * 8) + e;
        float w;
        if      (m < 8)  w = w1[m*C_+k];
        else if (m < 16) w = w2[(m-8)*C_+k];
        else if (m < 24) w = w11[(m-16)*C_+k];
        else if (m < 32) w = w22[(m-24)*C_+k];
        else             w = w3[(m-32)*C_+k];
        bf16 h = f2b(w);
        WfragUS[idx] = *(unsigned short*)&h;
    }
    if (tid < 96){
        int o = tid; float bb;
        if      (o < 8)  bb = b1[o];
        else if (o < 16) bb = b2[o-8];
        else if (o < 24) bb = b11[o-16];
        else if (o < 32) bb = b22[o-24];
        else             bb = b3[o-32];
        Bg[o] = bb;
    }
}

// K1 (MFMA): per block (n, 64-j tile): stage x fp32 in LDS; each wave owns a
// 16-j strip; 6 m-tiles x 2 k-steps of mfma_f32_16x16x32_bf16.
__global__ __launch_bounds__(256) void k1_mfma(
    const float* __restrict__ x,
    const unsigned short* __restrict__ WfragUS, const float* __restrict__ Bg,
    float* __restrict__ x1f, float* __restrict__ x2f,
    float* __restrict__ x11f, float* __restrict__ x22f,
    bf16* __restrict__ x3h)
{
    __shared__ __align__(16) float xl[C_*64];   // [c][j] 16KB
    __shared__ float Bl[96];
    int bid = blockIdx.x;
    int n = bid / 50, jt = bid % 50;
    int j0 = jt * 64;
    int tid = threadIdx.x;
    for (int e = tid; e < 1024; e += 256){
        int c = e >> 4, j4 = e & 15;
        ((float4*)xl)[e] = ((const float4*)(x + (size_t)(n*C_+c)*TV_ + j0))[j4];
    }
    if (tid < 96) Bl[tid] = Bg[tid];
    __syncthreads();

    int wave = tid >> 6, lane = tid & 63;
    int l15 = lane & 15, lg = lane >> 4;
    // A-fragments (global table, coalesced 16B/lane)
    const short8v* wf = (const short8v*)WfragUS;
    short8v a[6][2];
    #pragma unroll
    for (int mt = 0; mt < 6; ++mt)
        #pragma unroll
        for (int kb = 0; kb < 2; ++kb)
            a[mt][kb] = wf[(mt*2 + kb)*64 + lane];
    // B-fragments from LDS (k = kb*32 + lg*8 + e, j = this wave's strip + l15)
    int jw = wave*16 + l15;
    short8v b[2];
    #pragma unroll
    for (int kb = 0; kb < 2; ++kb){
        short8v bb;
        #pragma unroll
        for (int e = 0; e < 8; ++e){
            bf16 h = f2b(xl[(kb*32 + lg*8 + e)*64 + jw]);
            bb[e] = *(short*)&h;
        }
        b[kb] = bb;
    }
    float4v acc[6];
    #pragma unroll
    for (int mt = 0; mt < 6; ++mt) acc[mt] = (float4v){0.f,0.f,0.f,0.f};
    #pragma unroll
    for (int kb = 0; kb < 2; ++kb)
        #pragma unroll
        for (int mt = 0; mt < 6; ++mt)
            acc[mt] = __builtin_amdgcn_mfma_f32_16x16x32_bf16(a[mt][kb], b[kb], acc[mt], 0, 0, 0);

    int pos = j0 + jw;
    #pragma unroll
    for (int mt = 0; mt < 6; ++mt){
        #pragma unroll
        for (int reg = 0; reg < 4; ++reg){
            int o = mt*16 + lg*4 + reg;
            float val = acc[mt][reg] + Bl[o];
            if (o < 32){
                float* dst = (o < 8)  ? x1f  + ((size_t)(n*REL_ + o     ))*TV_
                           : (o < 16) ? x2f  + ((size_t)(n*REL_ + o - 8 ))*TV_
                           : (o < 24) ? x11f + ((size_t)(n*REL_ + o - 16))*TV_
                                      : x22f + ((size_t)(n*REL_ + o - 24))*TV_;
                dst[pos] = val;
            } else {
                x3h[((size_t)(n*OUT_ + o - 32))*TV_ + pos] = f2b(val);
            }
        }
    }
}

// Kx3bar v2: coalesced uint4 staging -> LDS fp32 -> two-level reduce.
__global__ __launch_bounds__(256) void k_x3bar2(const bf16* __restrict__ x3h,
                                                float* __restrict__ x3bar)
{
    __shared__ __align__(16) float xf[TV_];   // 12.8KB
    __shared__ float red[V_*8];
    int bid = blockIdx.x;   // n*OUT + c
    int tid = threadIdx.x;
    for (int e = tid; e < 400; e += 256){
        uint4 p = ((const uint4*)(x3h + (size_t)bid*TV_))[e];
        float* d = xf + e*8;
        d[0]=bfu(p.x); d[1]=bfh(p.x); d[2]=bfu(p.y); d[3]=bfh(p.y);
        d[4]=bfu(p.z); d[5]=bfh(p.z); d[6]=bfu(p.w); d[7]=bfh(p.w);
    }
    __syncthreads();
    if (tid < 200){
        int v = tid % V_, g = tid / V_;
        float s = 0.f;
        #pragma unroll
        for (int k=0;k<16;++k) s += xf[(g*16+k)*V_ + v];
        red[g*V_+v] = s;
    }
    __syncthreads();
    if (tid < V_){
        float s = 0.f;
        #pragma unroll
        for (int g=0; g<8; ++g) s += red[g*V_+tid];
        x3bar[(size_t)bid*V_+tid] = s * (1.0f/T_);
    }
}

// K3: att8 = tanh(x1^T x2 / T);  xm = tanh(w5_0*mean_res + w5_1*max_res + b5)*alpha
__global__ __launch_bounds__(256) void k3_att8_xm(
    const float* __restrict__ x1f, const float* __restrict__ x2f,
    const float* __restrict__ w5, const float* __restrict__ b5,
    const int* __restrict__ alpha,
    float* __restrict__ att8, float* __restrict__ xm)
{
    __shared__ __align__(16) float l1[TV_], l2[TV_];
    __shared__ float mu1l[V_], mu2l[V_], m1l[V_], m2l[V_];
    int bid = blockIdx.x;      // n*REL + r
    int tid = threadIdx.x;
    int r = bid % REL_;
    for (int e = tid; e < 800; e += 256){
        ((float4*)l1)[e] = ((const float4*)(x1f + (size_t)bid*TV_))[e];
        ((float4*)l2)[e] = ((const float4*)(x2f + (size_t)bid*TV_))[e];
    }
    __syncthreads();
    if (tid < 50){
        int v = tid % V_;
        const float* L = (tid < V_) ? l1 : l2;
        float s=0.f, mm=-1e30f;
        for (int t=0;t<T_;++t){
            float a = L[t*V_+v];
            s += a; mm = fmaxf(mm, a);
        }
        if (tid < V_){ mu1l[v]=s*(1.0f/T_); m1l[v]=mm; }
        else         { mu2l[v]=s*(1.0f/T_); m2l[v]=mm; }
    }
    __syncthreads();
    float w50=w5[r*2+0], w51=w5[r*2+1], b5r=b5[r];
    float af = (float)alpha[0];
    for (int idx=tid; idx<VV_; idx+=256){
        int u = idx/V_, v = idx%V_;
        float s=0.f;
        for (int t=0;t<T_;++t) s = fmaf(l1[t*V_+u], l2[t*V_+v], s);
        att8[(size_t)bid*VV_+idx] = ftanh(s*(1.0f/T_));
        float mr = mu1l[u]-mu2l[v];
        float xr = m1l[u]-m2l[v];
        xm[(size_t)bid*VV_+idx] = ftanh(fmaf(w50,mr,fmaf(w51,xr,b5r))) * af;
    }
}

// K6v2: channel attention; no attc materialization.
__global__ __launch_bounds__(256) void k6_chatt2(
    const float* __restrict__ att8, const float* __restrict__ x3bar,
    const float* __restrict__ watt, const float* __restrict__ batt,
    const float* __restrict__ wc1, const float* __restrict__ bc1,
    const float* __restrict__ bng, const float* __restrict__ bnb,
    const float* __restrict__ bnm, const float* __restrict__ bnv,
    const float* __restrict__ wc2, const float* __restrict__ bc2,
    float* __restrict__ catt)
{
    __shared__ float rs8[REL_*V_];
    __shared__ float gl[OUT_];
    __shared__ float hl[MID_];
    int n = blockIdx.x, tid = threadIdx.x;
    if (tid < REL_*V_){
        int r = tid / V_, u = tid % V_;
        const float* p = att8 + (size_t)(n*REL_+r)*VV_ + u*V_;
        float s = 0.f;
        #pragma unroll
        for (int v=0;v<V_;++v) s += p[v];
        rs8[tid] = s;
    }
    __syncthreads();
    if (tid < OUT_){
        int c = tid;
        const float* xb = x3bar + (size_t)(n*OUT_+c)*V_;
        float xbr[V_], sb = 0.f;
        #pragma unroll
        for (int u=0;u<V_;++u){ xbr[u]=xb[u]; sb += xbr[u]; }
        float s = 0.f;
        #pragma unroll
        for (int r=0;r<REL_;++r){
            float d = 0.f;
            #pragma unroll
            for (int u=0;u<V_;++u) d = fmaf(xbr[u], rs8[r*V_+u], d);
            s = fmaf(watt[c*REL_+r], d, s);
        }
        gl[c] = (s + (float)V_*batt[c]*sb) * (1.0f/(float)V_);
    }
    __syncthreads();
    if (tid < MID_){
        float h = bc1[tid];
        for (int c=0;c<OUT_;++c) h = fmaf(wc1[tid*OUT_+c], gl[c], h);
        h = (h - bnm[tid]) * bng[tid] * rsqrtf(bnv[tid] + 1e-5f) + bnb[tid];
        h = 0.5f*h*(1.0f+erff(h*0.70710678118654752f));
        hl[tid]=h;
    }
    __syncthreads();
    if (tid < OUT_){
        float s = bc2[tid];
        for (int m=0;m<MID_;++m) s = fmaf(wc2[tid*MID_+m], hl[m], s);
        catt[n*OUT_+tid] = 1.0f/(1.0f+expf(-s));
    }
}

// K8v3: s_att via c-sum pushed inward (no x1c read).
__global__ __launch_bounds__(256) void k8_satt3(
    const float* __restrict__ xm, const float* __restrict__ A,
    const float* __restrict__ catt, const float* __restrict__ x3bar,
    const float* __restrict__ w4, const float* __restrict__ b4,
    const float* __restrict__ wsp, const float* __restrict__ bsp,
    float* __restrict__ satt)
{
    __shared__ __align__(16) float xml[REL_*VV_];  // 20KB
    __shared__ __align__(16) float xbl[OUT_*V_];   // 6.4KB
    __shared__ float Al[VV_];
    __shared__ float w4l[OUT_*REL_];
    __shared__ float scl[OUT_];
    __shared__ float Wl[REL_*V_];
    __shared__ float Yl[V_];
    __shared__ float red[OUT_];
    int n = blockIdx.x, tid = threadIdx.x;
    for (int e=tid; e<1250; e+=256)
        ((float4*)xml)[e] = ((const float4*)(xm + (size_t)n*REL_*VV_))[e];
    for (int e=tid; e<400; e+=256)
        ((float4*)xbl)[e] = ((const float4*)(x3bar + (size_t)n*OUT_*V_))[e];
    for (int e=tid; e<VV_; e+=256) Al[e] = A[e];
    for (int e=tid; e<OUT_*REL_; e+=256) w4l[e] = w4[e];
    if (tid < OUT_) scl[tid] = wsp[tid]*catt[n*OUT_+tid];
    __syncthreads();
    if (tid < REL_*V_){
        int r = tid/V_, v = tid%V_;
        float s = 0.f;
        for (int c=0;c<OUT_;++c) s = fmaf(scl[c]*w4l[c*REL_+r], xbl[c*V_+v], s);
        Wl[tid] = s;
    } else if (tid < REL_*V_ + V_){
        int v = tid - REL_*V_;
        float s = 0.f;
        for (int c=0;c<OUT_;++c) s = fmaf(scl[c], xbl[c*V_+v], s);
        Yl[v] = s;
    }
    __syncthreads();
    if (tid < OUT_){
        float s1 = 0.f;
        #pragma unroll
        for (int v=0;v<V_;++v) s1 += xbl[tid*V_+v];
        red[tid] = scl[tid]*b4[tid]*s1;
    }
    __syncthreads();
    if (tid < V_){
        int u = tid;
        float acc = 0.f;
        #pragma unroll
        for (int r=0;r<REL_;++r){
            const float* xr = xml + r*VV_ + u*V_;
            const float* wr = Wl + r*V_;
            #pragma unroll
            for (int v=0;v<V_;++v) acc = fmaf(xr[v], wr[v], acc);
        }
        #pragma unroll
        for (int v=0;v<V_;++v) acc = fmaf(Al[u*V_+v], Yl[v], acc);
        float beta = 0.f;
        for (int c=0;c<OUT_;++c) beta += red[c];
        satt[n*V_+u] = 1.0f/(1.0f+expf(-(bsp[0]+acc+beta)));
    }
}

// Kcomb3: per (n,c): comb[t,w] = sum_u x3[t,u]*M[w,u], M built on the fly.
__global__ __launch_bounds__(256) void k_comb3(
    const bf16* __restrict__ x3h,
    const float* __restrict__ att8, const float* __restrict__ xm,
    const float* __restrict__ A,
    const float* __restrict__ watt, const float* __restrict__ batt,
    const float* __restrict__ w4, const float* __restrict__ b4,
    const float* __restrict__ catt, const float* __restrict__ satt,
    bf16* __restrict__ combh)
{
    __shared__ __align__(16) unsigned short x3s[TV_];   // 6.4KB
    __shared__ float Ml[VV_];
    __shared__ float sl[V_];
    __shared__ __align__(16) unsigned short cst[TV_];   // 6.4KB
    int bid = blockIdx.x;   // n*OUT + c
    int n = bid >> 6, c = bid & 63;
    int tid = threadIdx.x;
    for (int e = tid; e < 400; e += 256)
        ((uint4*)x3s)[e] = ((const uint4*)(x3h + (size_t)bid*TV_))[e];
    if (tid < V_) sl[tid] = satt[n*V_+tid];
    float ca = catt[bid];
    float w4r[REL_], war[REL_];
    #pragma unroll
    for (int r=0;r<REL_;++r){ w4r[r] = w4[c*REL_+r]; war[r] = watt[c*REL_+r]; }
    float b4c = b4[c], bac = batt[c];
    const float* xmn = xm  + (size_t)n*REL_*VV_;
    const float* a8n = att8 + (size_t)n*REL_*VV_;
    __syncthreads();
    for (int e = tid; e < VV_; e += 256){
        int w = e/V_, u = e%V_;
        float xv = b4c, av = bac;
        #pragma unroll
        for (int r=0;r<REL_;++r){
            xv = fmaf(w4r[r], xmn[r*VV_ + e], xv);
            av = fmaf(war[r], a8n[r*VV_ + u*V_ + w], av);
        }
        Ml[e] = ca*(xv + A[e]) + av*sl[w];
    }
    __syncthreads();
    int vh = tid & 1, tq = tid >> 1;
    int v0 = vh*13, nv = vh ? 12 : 13;
    float x3r[V_];
    #pragma unroll
    for (int u=0;u<V_;++u) x3r[u] = bfs(x3s[tq*V_+u]);
    for (int i=0;i<nv;++i){
        int v = v0+i;
        float s=0.f;
        #pragma unroll
        for (int u=0;u<V_;++u) s = fmaf(Ml[v*V_+u], x3r[u], s);
        bf16 h = f2b(s);
        cst[tq*V_+v] = *(unsigned short*)&h;
    }
    __syncthreads();
    for (int e = tid; e < 400; e += 256)
        ((uint4*)(combh + (size_t)bid*TV_))[e] = ((const uint4*)cst)[e];
}

// K10f7: R4 two-round structure, 512-thread blocks, wave-uniform v-split (acc[13]).
__global__ __launch_bounds__(512) void k10_final7(
    const float* __restrict__ x11f, const float* __restrict__ x22f,
    const bf16* __restrict__ x3h, const bf16* __restrict__ combh,
    const float* __restrict__ beita, float* __restrict__ out)
{
    __shared__ __align__(16) char stg[25600];                 // phase1: l11|l22 ; phase2: staging
    __shared__ __align__(16) unsigned short xtl[TT2*V_*XTP3]; // 16KB
    int bid = blockIdx.x;              // n*16 + tt
    int n = bid >> 4, tt = bid & 15;
    int t0 = tt * TT2;
    int tid = threadIdx.x;
    float* l11 = (float*)stg;          // [8][8][25]
    float* l22 = (float*)(stg + 6400);
    for (int e = tid; e < 400; e += 512){
        int r = e / 50, rem = e % 50;
        ((float4*)l11)[e] = ((const float4*)(x11f + (size_t)(n*REL_+r)*TV_ + t0*V_))[rem];
        ((float4*)l22)[e] = ((const float4*)(x22f + (size_t)(n*REL_+r)*TV_ + t0*V_))[rem];
    }
    __syncthreads();
    for (int e = tid; e < TT2*VV_; e += 512){
        int ti = e / VV_, uv = e % VV_;
        int u = uv / V_, v = uv % V_;
        float s = 0.f;
        #pragma unroll
        for (int r = 0; r < REL_; ++r)
            s = fmaf(l11[r*200 + ti*V_ + u], l22[r*200 + ti*V_ + v], s);
        bf16 h = f2b(ftanh(s * 0.125f));
        xtl[ti*(V_*XTP3) + u*XTP3 + v] = *(unsigned short*)&h;
    }
    float bt = beita[0];
    int vh = tid >> 8;                 // wave-uniform: waves 0-3 -> 0, 4-7 -> 1
    int c_local = (tid >> 3) & 31;
    int ti = tid & 7;
    for (int cr = 0; cr < 2; ++cr){
        int c0 = cr*32;
        __syncthreads();   // xtl ready (cr=0) / prev store done (cr=1)
        for (int e = tid; e < 1600; e += 512){
            int cl = e / 50, w = e % 50;
            size_t base = (size_t)(n*OUT_ + c0 + cl)*TV_ + (size_t)t0*V_;
            uint4 p = (w < 25) ? ((const uint4*)(combh + base))[w]
                               : ((const uint4*)(x3h  + base))[w-25];
            *(uint4*)(stg + cl*800 + (w<25 ? w*16 : 400 + (w-25)*16)) = p;
        }
        __syncthreads();
        const unsigned short* x3row = (const unsigned short*)(stg + c_local*800 + 400) + ti*V_;
        float acc[13];
        #pragma unroll
        for (int j=0;j<13;++j) acc[j]=0.f;
        int base_s = ti*(V_*XTP3) + vh*12;   // even short index -> uint-aligned
        #pragma unroll
        for (int u=0;u<V_;++u){
            float xa = bfs(x3row[u]);        // broadcast within vh pair
            const uint* xr = (const uint*)(xtl + base_s + u*XTP3);
            uint R[7];
            #pragma unroll
            for (int k=0;k<7;++k) R[k] = xr[k];
            if (vh == 0){
                #pragma unroll
                for (int k=0;k<6;++k){
                    acc[2*k]   = fmaf(xa, bfu(R[k]), acc[2*k]);
                    acc[2*k+1] = fmaf(xa, bfh(R[k]), acc[2*k+1]);
                }
                acc[12] = fmaf(xa, bfu(R[6]), acc[12]);
            } else {
                acc[0] = fmaf(xa, bfh(R[0]), acc[0]);
                #pragma unroll
                for (int k=1;k<6;++k){
                    acc[2*k-1] = fmaf(xa, bfu(R[k]), acc[2*k-1]);
                    acc[2*k]   = fmaf(xa, bfh(R[k]), acc[2*k]);
                }
                acc[11] = fmaf(xa, bfu(R[6]), acc[11]);
            }
        }
        const unsigned short* cmbrow =
            (const unsigned short*)(stg + c_local*800) + ti*V_ + vh*13;
        if (vh == 0){
            #pragma unroll
            for (int j=0;j<13;++j) acc[j] = fmaf(bt, acc[j], bfs(cmbrow[j]));
        } else {
            #pragma unroll
            for (int j=0;j<12;++j) acc[j] = fmaf(bt, acc[j], bfs(cmbrow[j]));
        }
        __syncthreads();   // all stage reads done before overwrite
        float* orow = (float*)(stg + c_local*800 + ti*100) + vh*13;
        if (vh == 0){
            #pragma unroll
            for (int j=0;j<13;++j) orow[j] = acc[j];
        } else {
            #pragma unroll
            for (int j=0;j<12;++j) orow[j] = acc[j];
        }
        __syncthreads();
        for (int e = tid; e < 1600; e += 512){
            int cl = e / 50, q = e % 50;
            *(float4*)(out + (size_t)(n*OUT_ + c0 + cl)*TV_ + (size_t)t0*V_ + q*4) =
                *(const float4*)(stg + cl*800 + q*16);
        }
    }
}

extern "C" void kernel_launch(void* const* d_in, const int* in_sizes, int n_in,
                              void* d_out, int out_size, void* d_ws, size_t ws_size,
                              hipStream_t stream)
{
    const float* x    = (const float*)d_in[0];
    const float* A    = (const float*)d_in[1];
    const float* w1   = (const float*)d_in[2];  const float* b1  = (const float*)d_in[3];
    const float* w2   = (const float*)d_in[4];  const float* b2  = (const float*)d_in[5];
    const float* w11  = (const float*)d_in[6];  const float* b11 = (const float*)d_in[7];
    const float* w22  = (const float*)d_in[8];  const float* b22 = (const float*)d_in[9];
    const float* w3   = (const float*)d_in[10]; const float* b3  = (const float*)d_in[11];
    const float* w4   = (const float*)d_in[12]; const float* b4  = (const float*)d_in[13];
    const float* watt = (const float*)d_in[14]; const float* batt= (const float*)d_in[15];
    const float* w5   = (const float*)d_in[16]; const float* b5  = (const float*)d_in[17];
    const float* wc1  = (const float*)d_in[18]; const float* bc1 = (const float*)d_in[19];
    const float* bng  = (const float*)d_in[20]; const float* bnb = (const float*)d_in[21];
    const float* bnm  = (const float*)d_in[22]; const float* bnv = (const float*)d_in[23];
    const float* wc2  = (const float*)d_in[24]; const float* bc2 = (const float*)d_in[25];
    const float* wsp  = (const float*)d_in[26]; const float* bsp = (const float*)d_in[27];
    const float* beita= (const float*)d_in[28];
    const int*  alpha = (const int*)d_in[29];
    float* out = (float*)d_out;

    char* wsb = (char*)d_ws;
    size_t off = 0;
    auto alloc = [&](size_t bytes)->char*{
        char* p = wsb + off;
        off += (bytes + 255) & ~(size_t)255;
        return p;
    };
    float* x1f   = (float*)alloc((size_t)N_*REL_*TV_*4);
    float* x2f   = (float*)alloc((size_t)N_*REL_*TV_*4);
    float* x11f  = (float*)alloc((size_t)N_*REL_*TV_*4);
    float* x22f  = (float*)alloc((size_t)N_*REL_*TV_*4);
    bf16*  x3h   = (bf16*) alloc((size_t)N_*OUT_*TV_*2);
    bf16*  combh = (bf16*) alloc((size_t)N_*OUT_*TV_*2);
    float* att8  = (float*)alloc((size_t)N_*REL_*VV_*4);
    float* xm    = (float*)alloc((size_t)N_*REL_*VV_*4);
    float* x3bar = (float*)alloc((size_t)N_*OUT_*V_*4);
    float* catt  = (float*)alloc((size_t)N_*OUT_*4);
    float* satt  = (float*)alloc((size_t)N_*V_*4);
    unsigned short* WfragUS = (unsigned short*)alloc((size_t)6144*2);
    float* Bg    = (float*)alloc((size_t)96*4);
    (void)ws_size; (void)n_in; (void)in_sizes; (void)out_size;

    k0_prep<<<1, 256, 0, stream>>>(w1,b1, w2,b2, w11,b11, w22,b22, w3,b3, WfragUS, Bg);
    k1_mfma<<<N_*50, 256, 0, stream>>>(x, WfragUS, Bg, x1f, x2f, x11f, x22f, x3h);
    k_x3bar2<<<N_*OUT_, 256, 0, stream>>>(x3h, x3bar);
    k3_att8_xm<<<N_*REL_, 256, 0, stream>>>(x1f, x2f, w5, b5, alpha, att8, xm);
    k6_chatt2<<<N_, 256, 0, stream>>>(att8, x3bar, watt, batt,
                                      wc1, bc1, bng, bnb, bnm, bnv, wc2, bc2, catt);
    k8_satt3<<<N_, 256, 0, stream>>>(xm, A, catt, x3bar, w4, b4, wsp, bsp, satt);
    k_comb3<<<N_*OUT_, 256, 0, stream>>>(x3h, att8, xm, A, watt, batt, w4, b4,
                                         catt, satt, combh);
    k10_final7<<<N_*16, 512, 0, stream>>>(x11f, x22f, x3h, combh, beita, out);
}

// Round 16
// 136.423 us; speedup vs baseline: 1.3391x; 1.0376x over previous
//
#include <hip/hip_runtime.h>
#include <hip/hip_bf16.h>
#include <math.h>

#define N_   64
#define C_   64
#define T_   128
#define V_   25
#define OUT_ 64
#define REL_ 8
#define MID_ 32
#define TV_  (T_*V_)   // 3200
#define VV_  (V_*V_)   // 625
#define TT2  8         // t-tile for fused temporal kernel
#define XTP3 40        // xtl row pad in shorts (80B: 16B-aligned rows)

typedef __hip_bfloat16 bf16;
typedef unsigned int uint;
typedef __attribute__((ext_vector_type(8))) short short8v;   // 8 bf16 (4 VGPR)
typedef __attribute__((ext_vector_type(4))) float float4v;   // MFMA accum
__device__ __forceinline__ float b2f(bf16 x){ return __bfloat162float(x); }
__device__ __forceinline__ bf16  f2b(float x){ return __float2bfloat16(x); }
__device__ __forceinline__ float bfu(uint u){ return __uint_as_float(u<<16); }
__device__ __forceinline__ float bfh(uint u){ return __uint_as_float(u&0xffff0000u); }
__device__ __forceinline__ float bfs(unsigned short s){ return __uint_as_float(((uint)s)<<16); }

// fast tanh: clamp + (e^{2x}-1)/(e^{2x}+1); abs err ~1e-6, threshold 1.9e-2.
__device__ __forceinline__ float ftanh(float x){
    float cx = fminf(fmaxf(x, -15.f), 15.f);
    float e  = __expf(2.0f*cx);
    return (e - 1.0f) / (e + 1.0f);
}

// LESSONS (measured, R4-R15):
//  * launch_bounds min-waves caps -> VGPR spill -> GBs scratch traffic. Banned.
//  * k10 acc[25]->acc[13] wave-uniform v-split: 87->~48us (R12/R15).
//  * k1 scalar-FMA plateaued 56-72us; MFMA formulation fixed it (R15, absmax
//    unchanged -> A-frag m=lane&15,k=(lane>>4)*8+e / C col=lane&15,
//    row=(lane>>4)*4+reg layout is HW-verified end-to-end).
//  * R16: x1/x2/x11/x22 stored bf16 (halves traffic); k3 -> MFMA (K=128 GEMM).

// K0: build bf16 A-fragment table WfragUS[mt][kb][lane][e] + biases Bg[96].
__global__ __launch_bounds__(256) void k0_prep(
    const float* __restrict__ w1, const float* __restrict__ b1,
    const float* __restrict__ w2, const float* __restrict__ b2,
    const float* __restrict__ w11, const float* __restrict__ b11,
    const float* __restrict__ w22, const float* __restrict__ b22,
    const float* __restrict__ w3, const float* __restrict__ b3,
    unsigned short* __restrict__ WfragUS, float* __restrict__ Bg)
{
    int tid = threadIdx.x;
    for (int idx = tid; idx < 6144; idx += 256){
        int e  = idx & 7;
        int ln = (idx >> 3) & 63;
        int kb = (idx >> 9) & 1;
        int mt = idx >> 10;
        int m = mt*16 + (ln & 15);
        int k = kb*32 + ((ln >> 4) * 8) + e;
        float w;
        if      (m < 8)  w = w1[m*C_+k];
        else if (m < 16) w = w2[(m-8)*C_+k];
        else if (m < 24) w = w11[(m-16)*C_+k];
        else if (m < 32) w = w22[(m-24)*C_+k];
        else             w = w3[(m-32)*C_+k];
        bf16 h = f2b(w);
        WfragUS[idx] = *(unsigned short*)&h;
    }
    if (tid < 96){
        int o = tid; float bb;
        if      (o < 8)  bb = b1[o];
        else if (o < 16) bb = b2[o-8];
        else if (o < 24) bb = b11[o-16];
        else if (o < 32) bb = b22[o-24];
        else             bb = b3[o-32];
        Bg[o] = bb;
    }
}

// K1 (MFMA): per block (n, 64-j tile). ALL outputs stored bf16 now.
__global__ __launch_bounds__(256) void k1_mfma(
    const float* __restrict__ x,
    const unsigned short* __restrict__ WfragUS, const float* __restrict__ Bg,
    bf16* __restrict__ x1h, bf16* __restrict__ x2h,
    bf16* __restrict__ x11h, bf16* __restrict__ x22h,
    bf16* __restrict__ x3h)
{
    __shared__ __align__(16) float xl[C_*64];   // [c][j] 16KB
    __shared__ float Bl[96];
    int bid = blockIdx.x;
    int n = bid / 50, jt = bid % 50;
    int j0 = jt * 64;
    int tid = threadIdx.x;
    for (int e = tid; e < 1024; e += 256){
        int c = e >> 4, j4 = e & 15;
        ((float4*)xl)[e] = ((const float4*)(x + (size_t)(n*C_+c)*TV_ + j0))[j4];
    }
    if (tid < 96) Bl[tid] = Bg[tid];
    __syncthreads();

    int wave = tid >> 6, lane = tid & 63;
    int l15 = lane & 15, lg = lane >> 4;
    const short8v* wf = (const short8v*)WfragUS;
    short8v a[6][2];
    #pragma unroll
    for (int mt = 0; mt < 6; ++mt)
        #pragma unroll
        for (int kb = 0; kb < 2; ++kb)
            a[mt][kb] = wf[(mt*2 + kb)*64 + lane];
    int jw = wave*16 + l15;
    short8v b[2];
    #pragma unroll
    for (int kb = 0; kb < 2; ++kb){
        short8v bb;
        #pragma unroll
        for (int e = 0; e < 8; ++e){
            bf16 h = f2b(xl[(kb*32 + lg*8 + e)*64 + jw]);
            bb[e] = *(short*)&h;
        }
        b[kb] = bb;
    }
    float4v acc[6];
    #pragma unroll
    for (int mt = 0; mt < 6; ++mt) acc[mt] = (float4v){0.f,0.f,0.f,0.f};
    #pragma unroll
    for (int kb = 0; kb < 2; ++kb)
        #pragma unroll
        for (int mt = 0; mt < 6; ++mt)
            acc[mt] = __builtin_amdgcn_mfma_f32_16x16x32_bf16(a[mt][kb], b[kb], acc[mt], 0, 0, 0);

    int pos = j0 + jw;
    #pragma unroll
    for (int mt = 0; mt < 6; ++mt){
        #pragma unroll
        for (int reg = 0; reg < 4; ++reg){
            int o = mt*16 + lg*4 + reg;
            float val = acc[mt][reg] + Bl[o];
            bf16* dst = (o < 8)  ? x1h  + ((size_t)(n*REL_ + o     ))*TV_
                      : (o < 16) ? x2h  + ((size_t)(n*REL_ + o - 8 ))*TV_
                      : (o < 24) ? x11h + ((size_t)(n*REL_ + o - 16))*TV_
                      : (o < 32) ? x22h + ((size_t)(n*REL_ + o - 24))*TV_
                                 : x3h  + ((size_t)(n*OUT_ + o - 32))*TV_;
            dst[pos] = f2b(val);
        }
    }
}

// Kx3bar v2: coalesced uint4 staging -> LDS fp32 -> two-level reduce.
__global__ __launch_bounds__(256) void k_x3bar2(const bf16* __restrict__ x3h,
                                                float* __restrict__ x3bar)
{
    __shared__ __align__(16) float xf[TV_];   // 12.8KB
    __shared__ float red[V_*8];
    int bid = blockIdx.x;   // n*OUT + c
    int tid = threadIdx.x;
    for (int e = tid; e < 400; e += 256){
        uint4 p = ((const uint4*)(x3h + (size_t)bid*TV_))[e];
        float* d = xf + e*8;
        d[0]=bfu(p.x); d[1]=bfh(p.x); d[2]=bfu(p.y); d[3]=bfh(p.y);
        d[4]=bfu(p.z); d[5]=bfh(p.z); d[6]=bfu(p.w); d[7]=bfh(p.w);
    }
    __syncthreads();
    if (tid < 200){
        int v = tid % V_, g = tid / V_;
        float s = 0.f;
        #pragma unroll
        for (int k=0;k<16;++k) s += xf[(g*16+k)*V_ + v];
        red[g*V_+v] = s;
    }
    __syncthreads();
    if (tid < V_){
        float s = 0.f;
        #pragma unroll
        for (int g=0; g<8; ++g) s += red[g*V_+tid];
        x3bar[(size_t)bid*V_+tid] = s * (1.0f/T_);
    }
}

// K3 (MFMA): att8[u,v] = tanh( sum_t x1[t,u]*x2[t,v] / T ) via 16x16x32 bf16
// (M=N=25 zero-padded, K=128 in 4 steps; wave w owns tile (mt=w>>1, nt=w&1)).
// xm computed elementwise from fp32 stats of the staged bf16 tiles.
__global__ __launch_bounds__(256) void k3_mfma(
    const bf16* __restrict__ x1h, const bf16* __restrict__ x2h,
    const float* __restrict__ w5, const float* __restrict__ b5,
    const int* __restrict__ alpha,
    float* __restrict__ att8, float* __restrict__ xm)
{
    __shared__ __align__(16) unsigned short l1[TV_], l2[TV_];   // 6.4KB each
    __shared__ float mu1l[V_], mu2l[V_], m1l[V_], m2l[V_];
    int bid = blockIdx.x;      // n*REL + r
    int tid = threadIdx.x;
    int r = bid % REL_;
    for (int e = tid; e < 400; e += 256){
        ((uint4*)l1)[e] = ((const uint4*)(x1h + (size_t)bid*TV_))[e];
        ((uint4*)l2)[e] = ((const uint4*)(x2h + (size_t)bid*TV_))[e];
    }
    __syncthreads();
    if (tid < 50){
        int v = tid % V_;
        const unsigned short* L = (tid < V_) ? l1 : l2;
        float s=0.f, mm=-1e30f;
        for (int t=0;t<T_;++t){
            float a = bfs(L[t*V_+v]);
            s += a; mm = fmaxf(mm, a);
        }
        if (tid < V_){ mu1l[v]=s*(1.0f/T_); m1l[v]=mm; }
        else         { mu2l[v]=s*(1.0f/T_); m2l[v]=mm; }
    }
    __syncthreads();
    // MFMA: C[u][v] = sum_t A[u][t]*B[t][v], A=x1^T, B=x2.
    int wave = tid >> 6, lane = tid & 63;
    int l15 = lane & 15, lg = lane >> 4;
    int mt = wave >> 1, nt = wave & 1;
    int mu = mt*16 + l15;     // A row (u)
    int nv = nt*16 + l15;     // B col (v)
    float4v acc = (float4v){0.f,0.f,0.f,0.f};
    #pragma unroll
    for (int kb = 0; kb < 4; ++kb){
        short8v av, bv;
        #pragma unroll
        for (int e = 0; e < 8; ++e){
            int k = kb*32 + lg*8 + e;   // t index, 0..127
            av[e] = (mu < V_) ? (short)l1[k*V_ + mu] : (short)0;
            bv[e] = (nv < V_) ? (short)l2[k*V_ + nv] : (short)0;
        }
        acc = __builtin_amdgcn_mfma_f32_16x16x32_bf16(av, bv, acc, 0, 0, 0);
    }
    #pragma unroll
    for (int reg = 0; reg < 4; ++reg){
        int u = mt*16 + lg*4 + reg;
        if (u < V_ && nv < V_)
            att8[(size_t)bid*VV_ + u*V_ + nv] = ftanh(acc[reg]*(1.0f/T_));
    }
    // xm elementwise from stats
    float w50=w5[r*2+0], w51=w5[r*2+1], b5r=b5[r];
    float af = (float)alpha[0];
    for (int idx=tid; idx<VV_; idx+=256){
        int u = idx/V_, v = idx%V_;
        float mr = mu1l[u]-mu2l[v];
        float xr = m1l[u]-m2l[v];
        xm[(size_t)bid*VV_+idx] = ftanh(fmaf(w50,mr,fmaf(w51,xr,b5r))) * af;
    }
}

// K6v2: channel attention; no attc materialization.
__global__ __launch_bounds__(256) void k6_chatt2(
    const float* __restrict__ att8, const float* __restrict__ x3bar,
    const float* __restrict__ watt, const float* __restrict__ batt,
    const float* __restrict__ wc1, const float* __restrict__ bc1,
    const float* __restrict__ bng, const float* __restrict__ bnb,
    const float* __restrict__ bnm, const float* __restrict__ bnv,
    const float* __restrict__ wc2, const float* __restrict__ bc2,
    float* __restrict__ catt)
{
    __shared__ float rs8[REL_*V_];
    __shared__ float gl[OUT_];
    __shared__ float hl[MID_];
    int n = blockIdx.x, tid = threadIdx.x;
    if (tid < REL_*V_){
        int r = tid / V_, u = tid % V_;
        const float* p = att8 + (size_t)(n*REL_+r)*VV_ + u*V_;
        float s = 0.f;
        #pragma unroll
        for (int v=0;v<V_;++v) s += p[v];
        rs8[tid] = s;
    }
    __syncthreads();
    if (tid < OUT_){
        int c = tid;
        const float* xb = x3bar + (size_t)(n*OUT_+c)*V_;
        float xbr[V_], sb = 0.f;
        #pragma unroll
        for (int u=0;u<V_;++u){ xbr[u]=xb[u]; sb += xbr[u]; }
        float s = 0.f;
        #pragma unroll
        for (int r=0;r<REL_;++r){
            float d = 0.f;
            #pragma unroll
            for (int u=0;u<V_;++u) d = fmaf(xbr[u], rs8[r*V_+u], d);
            s = fmaf(watt[c*REL_+r], d, s);
        }
        gl[c] = (s + (float)V_*batt[c]*sb) * (1.0f/(float)V_);
    }
    __syncthreads();
    if (tid < MID_){
        float h = bc1[tid];
        for (int c=0;c<OUT_;++c) h = fmaf(wc1[tid*OUT_+c], gl[c], h);
        h = (h - bnm[tid]) * bng[tid] * rsqrtf(bnv[tid] + 1e-5f) + bnb[tid];
        h = 0.5f*h*(1.0f+erff(h*0.70710678118654752f));
        hl[tid]=h;
    }
    __syncthreads();
    if (tid < OUT_){
        float s = bc2[tid];
        for (int m=0;m<MID_;++m) s = fmaf(wc2[tid*MID_+m], hl[m], s);
        catt[n*OUT_+tid] = 1.0f/(1.0f+expf(-s));
    }
}

// K8v3: s_att via c-sum pushed inward (no x1c read).
__global__ __launch_bounds__(256) void k8_satt3(
    const float* __restrict__ xm, const float* __restrict__ A,
    const float* __restrict__ catt, const float* __restrict__ x3bar,
    const float* __restrict__ w4, const float* __restrict__ b4,
    const float* __restrict__ wsp, const float* __restrict__ bsp,
    float* __restrict__ satt)
{
    __shared__ __align__(16) float xml[REL_*VV_];  // 20KB
    __shared__ __align__(16) float xbl[OUT_*V_];   // 6.4KB
    __shared__ float Al[VV_];
    __shared__ float w4l[OUT_*REL_];
    __shared__ float scl[OUT_];
    __shared__ float Wl[REL_*V_];
    __shared__ float Yl[V_];
    __shared__ float red[OUT_];
    int n = blockIdx.x, tid = threadIdx.x;
    for (int e=tid; e<1250; e+=256)
        ((float4*)xml)[e] = ((const float4*)(xm + (size_t)n*REL_*VV_))[e];
    for (int e=tid; e<400; e+=256)
        ((float4*)xbl)[e] = ((const float4*)(x3bar + (size_t)n*OUT_*V_))[e];
    for (int e=tid; e<VV_; e+=256) Al[e] = A[e];
    for (int e=tid; e<OUT_*REL_; e+=256) w4l[e] = w4[e];
    if (tid < OUT_) scl[tid] = wsp[tid]*catt[n*OUT_+tid];
    __syncthreads();
    if (tid < REL_*V_){
        int r = tid/V_, v = tid%V_;
        float s = 0.f;
        for (int c=0;c<OUT_;++c) s = fmaf(scl[c]*w4l[c*REL_+r], xbl[c*V_+v], s);
        Wl[tid] = s;
    } else if (tid < REL_*V_ + V_){
        int v = tid - REL_*V_;
        float s = 0.f;
        for (int c=0;c<OUT_;++c) s = fmaf(scl[c], xbl[c*V_+v], s);
        Yl[v] = s;
    }
    __syncthreads();
    if (tid < OUT_){
        float s1 = 0.f;
        #pragma unroll
        for (int v=0;v<V_;++v) s1 += xbl[tid*V_+v];
        red[tid] = scl[tid]*b4[tid]*s1;
    }
    __syncthreads();
    if (tid < V_){
        int u = tid;
        float acc = 0.f;
        #pragma unroll
        for (int r=0;r<REL_;++r){
            const float* xr = xml + r*VV_ + u*V_;
            const float* wr = Wl + r*V_;
            #pragma unroll
            for (int v=0;v<V_;++v) acc = fmaf(xr[v], wr[v], acc);
        }
        #pragma unroll
        for (int v=0;v<V_;++v) acc = fmaf(Al[u*V_+v], Yl[v], acc);
        float beta = 0.f;
        for (int c=0;c<OUT_;++c) beta += red[c];
        satt[n*V_+u] = 1.0f/(1.0f+expf(-(bsp[0]+acc+beta)));
    }
}

// Kcomb3: per (n,c): comb[t,w] = sum_u x3[t,u]*M[w,u], M built on the fly.
__global__ __launch_bounds__(256) void k_comb3(
    const bf16* __restrict__ x3h,
    const float* __restrict__ att8, const float* __restrict__ xm,
    const float* __restrict__ A,
    const float* __restrict__ watt, const float* __restrict__ batt,
    const float* __restrict__ w4, const float* __restrict__ b4,
    const float* __restrict__ catt, const float* __restrict__ satt,
    bf16* __restrict__ combh)
{
    __shared__ __align__(16) unsigned short x3s[TV_];   // 6.4KB
    __shared__ float Ml[VV_];
    __shared__ float sl[V_];
    __shared__ __align__(16) unsigned short cst[TV_];   // 6.4KB
    int bid = blockIdx.x;   // n*OUT + c
    int n = bid >> 6, c = bid & 63;
    int tid = threadIdx.x;
    for (int e = tid; e < 400; e += 256)
        ((uint4*)x3s)[e] = ((const uint4*)(x3h + (size_t)bid*TV_))[e];
    if (tid < V_) sl[tid] = satt[n*V_+tid];
    float ca = catt[bid];
    float w4r[REL_], war[REL_];
    #pragma unroll
    for (int r=0;r<REL_;++r){ w4r[r] = w4[c*REL_+r]; war[r] = watt[c*REL_+r]; }
    float b4c = b4[c], bac = batt[c];
    const float* xmn = xm  + (size_t)n*REL_*VV_;
    const float* a8n = att8 + (size_t)n*REL_*VV_;
    __syncthreads();
    for (int e = tid; e < VV_; e += 256){
        int w = e/V_, u = e%V_;
        float xv = b4c, av = bac;
        #pragma unroll
        for (int r=0;r<REL_;++r){
            xv = fmaf(w4r[r], xmn[r*VV_ + e], xv);
            av = fmaf(war[r], a8n[r*VV_ + u*V_ + w], av);
        }
        Ml[e] = ca*(xv + A[e]) + av*sl[w];
    }
    __syncthreads();
    int vh = tid & 1, tq = tid >> 1;
    int v0 = vh*13, nv = vh ? 12 : 13;
    float x3r[V_];
    #pragma unroll
    for (int u=0;u<V_;++u) x3r[u] = bfs(x3s[tq*V_+u]);
    for (int i=0;i<nv;++i){
        int v = v0+i;
        float s=0.f;
        #pragma unroll
        for (int u=0;u<V_;++u) s = fmaf(Ml[v*V_+u], x3r[u], s);
        bf16 h = f2b(s);
        cst[tq*V_+v] = *(unsigned short*)&h;
    }
    __syncthreads();
    for (int e = tid; e < 400; e += 256)
        ((uint4*)(combh + (size_t)bid*TV_))[e] = ((const uint4*)cst)[e];
}

// K10f7: R4 two-round structure, 512-thread blocks, wave-uniform v-split (acc[13]).
// x11/x22 now bf16: unpack-on-stage into fp32 LDS (loops unchanged downstream).
__global__ __launch_bounds__(512) void k10_final7(
    const bf16* __restrict__ x11h, const bf16* __restrict__ x22h,
    const bf16* __restrict__ x3h, const bf16* __restrict__ combh,
    const float* __restrict__ beita, float* __restrict__ out)
{
    __shared__ __align__(16) char stg[25600];                 // phase1: l11|l22 fp32 ; phase2: staging
    __shared__ __align__(16) unsigned short xtl[TT2*V_*XTP3]; // 16KB
    int bid = blockIdx.x;              // n*16 + tt
    int n = bid >> 4, tt = bid & 15;
    int t0 = tt * TT2;
    int tid = threadIdx.x;
    float* l11 = (float*)stg;          // [8][8][25] fp32
    float* l22 = (float*)(stg + 6400);
    for (int e = tid; e < 400; e += 512){
        int half = (e >= 200);
        int i = half ? e-200 : e;          // 25 uint4 chunks per r
        int r = i / 25, ch = i % 25;
        const bf16* src = (half ? x22h : x11h) + (size_t)(n*REL_+r)*TV_ + t0*V_ + ch*8;
        uint4 p = *(const uint4*)src;
        float* d = (half ? l22 : l11) + i*8;
        d[0]=bfu(p.x); d[1]=bfh(p.x); d[2]=bfu(p.y); d[3]=bfh(p.y);
        d[4]=bfu(p.z); d[5]=bfh(p.z); d[6]=bfu(p.w); d[7]=bfh(p.w);
    }
    __syncthreads();
    for (int e = tid; e < TT2*VV_; e += 512){
        int ti = e / VV_, uv = e % VV_;
        int u = uv / V_, v = uv % V_;
        float s = 0.f;
        #pragma unroll
        for (int r = 0; r < REL_; ++r)
            s = fmaf(l11[r*200 + ti*V_ + u], l22[r*200 + ti*V_ + v], s);
        bf16 h = f2b(ftanh(s * 0.125f));
        xtl[ti*(V_*XTP3) + u*XTP3 + v] = *(unsigned short*)&h;
    }
    float bt = beita[0];
    int vh = tid >> 8;                 // wave-uniform
    int c_local = (tid >> 3) & 31;
    int ti = tid & 7;
    for (int cr = 0; cr < 2; ++cr){
        int c0 = cr*32;
        __syncthreads();   // xtl ready (cr=0) / prev store done (cr=1)
        for (int e = tid; e < 1600; e += 512){
            int cl = e / 50, w = e % 50;
            size_t base = (size_t)(n*OUT_ + c0 + cl)*TV_ + (size_t)t0*V_;
            uint4 p = (w < 25) ? ((const uint4*)(combh + base))[w]
                               : ((const uint4*)(x3h  + base))[w-25];
            *(uint4*)(stg + cl*800 + (w<25 ? w*16 : 400 + (w-25)*16)) = p;
        }
        __syncthreads();
        const unsigned short* x3row = (const unsigned short*)(stg + c_local*800 + 400) + ti*V_;
        float acc[13];
        #pragma unroll
        for (int j=0;j<13;++j) acc[j]=0.f;
        int base_s = ti*(V_*XTP3) + vh*12;
        #pragma unroll
        for (int u=0;u<V_;++u){
            float xa = bfs(x3row[u]);
            const uint* xr = (const uint*)(xtl + base_s + u*XTP3);
            uint R[7];
            #pragma unroll
            for (int k=0;k<7;++k) R[k] = xr[k];
            if (vh == 0){
                #pragma unroll
                for (int k=0;k<6;++k){
                    acc[2*k]   = fmaf(xa, bfu(R[k]), acc[2*k]);
                    acc[2*k+1] = fmaf(xa, bfh(R[k]), acc[2*k+1]);
                }
                acc[12] = fmaf(xa, bfu(R[6]), acc[12]);
            } else {
                acc[0] = fmaf(xa, bfh(R[0]), acc[0]);
                #pragma unroll
                for (int k=1;k<6;++k){
                    acc[2*k-1] = fmaf(xa, bfu(R[k]), acc[2*k-1]);
                    acc[2*k]   = fmaf(xa, bfh(R[k]), acc[2*k]);
                }
                acc[11] = fmaf(xa, bfu(R[6]), acc[11]);
            }
        }
        const unsigned short* cmbrow =
            (const unsigned short*)(stg + c_local*800) + ti*V_ + vh*13;
        if (vh == 0){
            #pragma unroll
            for (int j=0;j<13;++j) acc[j] = fmaf(bt, acc[j], bfs(cmbrow[j]));
        } else {
            #pragma unroll
            for (int j=0;j<12;++j) acc[j] = fmaf(bt, acc[j], bfs(cmbrow[j]));
        }
        __syncthreads();   // all stage reads done before overwrite
        float* orow = (float*)(stg + c_local*800 + ti*100) + vh*13;
        if (vh == 0){
            #pragma unroll
            for (int j=0;j<13;++j) orow[j] = acc[j];
        } else {
            #pragma unroll
            for (int j=0;j<12;++j) orow[j] = acc[j];
        }
        __syncthreads();
        for (int e = tid; e < 1600; e += 512){
            int cl = e / 50, q = e % 50;
            *(float4*)(out + (size_t)(n*OUT_ + c0 + cl)*TV_ + (size_t)t0*V_ + q*4) =
                *(const float4*)(stg + cl*800 + q*16);
        }
    }
}

extern "C" void kernel_launch(void* const* d_in, const int* in_sizes, int n_in,
                              void* d_out, int out_size, void* d_ws, size_t ws_size,
                              hipStream_t stream)
{
    const float* x    = (const float*)d_in[0];
    const float* A    = (const float*)d_in[1];
    const float* w1   = (const float*)d_in[2];  const float* b1  = (const float*)d_in[3];
    const float* w2   = (const float*)d_in[4];  const float* b2  = (const float*)d_in[5];
    const float* w11  = (const float*)d_in[6];  const float* b11 = (const float*)d_in[7];
    const float* w22  = (const float*)d_in[8];  const float* b22 = (const float*)d_in[9];
    const float* w3   = (const float*)d_in[10]; const float* b3  = (const float*)d_in[11];
    const float* w4   = (const float*)d_in[12]; const float* b4  = (const float*)d_in[13];
    const float* watt = (const float*)d_in[14]; const float* batt= (const float*)d_in[15];
    const float* w5   = (const float*)d_in[16]; const float* b5  = (const float*)d_in[17];
    const float* wc1  = (const float*)d_in[18]; const float* bc1 = (const float*)d_in[19];
    const float* bng  = (const float*)d_in[20]; const float* bnb = (const float*)d_in[21];
    const float* bnm  = (const float*)d_in[22]; const float* bnv = (const float*)d_in[23];
    const float* wc2  = (const float*)d_in[24]; const float* bc2 = (const float*)d_in[25];
    const float* wsp  = (const float*)d_in[26]; const float* bsp = (const float*)d_in[27];
    const float* beita= (const float*)d_in[28];
    const int*  alpha = (const int*)d_in[29];
    float* out = (float*)d_out;

    char* wsb = (char*)d_ws;
    size_t off = 0;
    auto alloc = [&](size_t bytes)->char*{
        char* p = wsb + off;
        off += (bytes + 255) & ~(size_t)255;
        return p;
    };
    bf16*  x1h   = (bf16*) alloc((size_t)N_*REL_*TV_*2);
    bf16*  x2h   = (bf16*) alloc((size_t)N_*REL_*TV_*2);
    bf16*  x11h  = (bf16*) alloc((size_t)N_*REL_*TV_*2);
    bf16*  x22h  = (bf16*) alloc((size_t)N_*REL_*TV_*2);
    bf16*  x3h   = (bf16*) alloc((size_t)N_*OUT_*TV_*2);
    bf16*  combh = (bf16*) alloc((size_t)N_*OUT_*TV_*2);
    float* att8  = (float*)alloc((size_t)N_*REL_*VV_*4);
    float* xm    = (float*)alloc((size_t)N_*REL_*VV_*4);
    float* x3bar = (float*)alloc((size_t)N_*OUT_*V_*4);
    float* catt  = (float*)alloc((size_t)N_*OUT_*4);
    float* satt  = (float*)alloc((size_t)N_*V_*4);
    unsigned short* WfragUS = (unsigned short*)alloc((size_t)6144*2);
    float* Bg    = (float*)alloc((size_t)96*4);
    (void)ws_size; (void)n_in; (void)in_sizes; (void)out_size;

    k0_prep<<<1, 256, 0, stream>>>(w1,b1, w2,b2, w11,b11, w22,b22, w3,b3, WfragUS, Bg);
    k1_mfma<<<N_*50, 256, 0, stream>>>(x, WfragUS, Bg, x1h, x2h, x11h, x22h, x3h);
    k_x3bar2<<<N_*OUT_, 256, 0, stream>>>(x3h, x3bar);
    k3_mfma<<<N_*REL_, 256, 0, stream>>>(x1h, x2h, w5, b5, alpha, att8, xm);
    k6_chatt2<<<N_, 256, 0, stream>>>(att8, x3bar, watt, batt,
                                      wc1, bc1, bng, bnb, bnm, bnv, wc2, bc2, catt);
    k8_satt3<<<N_, 256, 0, stream>>>(xm, A, catt, x3bar, w4, b4, wsp, bsp, satt);
    k_comb3<<<N_*OUT_, 256, 0, stream>>>(x3h, att8, xm, A, watt, batt, w4, b4,
                                         catt, satt, combh);
    k10_final7<<<N_*16, 512, 0, stream>>>(x11h, x22h, x3h, combh, beita, out);
}